// Round 5
// baseline (770.874 us; speedup 1.0000x reference)
//
#include <hip/hip_runtime.h>
#include <math.h>

#define NNODE 50000
#define NEDGE 800000
#define DINv  128
#define EDv   16
#define NHv   4
#define CHv   128
#define HCv   512
#define SLOPEv 0.2f
#define MEANBLK 512
#define CONVN (NNODE * DINv / 4)

typedef __attribute__((ext_vector_type(8))) short bf16x8;
typedef __attribute__((ext_vector_type(4))) float f32x4;
typedef __attribute__((address_space(3))) unsigned lds_u32;
typedef const __attribute__((address_space(1))) unsigned glb_u32;

__device__ __forceinline__ ushort f2b(float f) {
  unsigned u = __float_as_uint(f);
  u += 0x7FFF + ((u >> 16) & 1);
  return (ushort)(u >> 16);
}
__device__ __forceinline__ float blo(unsigned u) { return __uint_as_float(u << 16); }
__device__ __forceinline__ float bhi(unsigned u) { return __uint_as_float(u & 0xffff0000u); }

// ---------------------------------------------------------------- CSR build
__global__ void detect_kernel(const int* __restrict__ ei, int* __restrict__ flag) {
  __shared__ int bad;
  if (threadIdx.x == 0) bad = 0;
  __syncthreads();
  for (int i = threadIdx.x; i < 2048; i += 256)
    if (ei[2 * i + 1] != 0) bad = 1;
  __syncthreads();
  if (threadIdx.x == 0) flag[0] = bad ? 0 : 1;
}

__device__ __forceinline__ int load_idx(const int* __restrict__ ei, int e, int row, int wide) {
  if (wide) return ei[2 * ((size_t)row * NEDGE + e)];
  return ei[(size_t)row * NEDGE + e];
}

__global__ void count_kernel(const int* __restrict__ ei, const int* __restrict__ flag,
                             int* __restrict__ deg) {
  int e = blockIdx.x * blockDim.x + threadIdx.x;
  if (e < NEDGE) {
    int w = flag[0];
    atomicAdd(&deg[load_idx(ei, e, 1, w)], 1);
  }
}

// shfl-based single-block scan, 4 elements/thread (13 serial chunks)
__global__ __launch_bounds__(1024) void scan_kernel(const int* __restrict__ deg,
                                                    int* __restrict__ row_ptr) {
  __shared__ int wsum[16];
  int tid = threadIdx.x;
  int wid = tid >> 6, lane = tid & 63;
  int carry = 0;
  for (int base = 0; base < NNODE; base += 4096) {
    int idx = base + tid * 4;
    int4 x = make_int4(0, 0, 0, 0);
    if (idx < NNODE) x = *(const int4*)(deg + idx);   // NNODE % 4 == 0
    int t0 = x.x, t1 = t0 + x.y, t2 = t1 + x.z, t3 = t2 + x.w;
    int v = t3;
#pragma unroll
    for (int off = 1; off < 64; off <<= 1) {
      int t = __shfl_up(v, off, 64);
      if (lane >= off) v += t;
    }
    if (lane == 63) wsum[wid] = v;
    __syncthreads();
    if (wid == 0) {
      int s = (lane < 16) ? wsum[lane] : 0;
#pragma unroll
      for (int off = 1; off < 16; off <<= 1) {
        int t = __shfl_up(s, off, 64);
        if (lane >= off) s += t;
      }
      if (lane < 16) wsum[lane] = s;
    }
    __syncthreads();
    int woff = wid ? wsum[wid - 1] : 0;
    int excl = carry + woff + v - t3;
    if (idx < NNODE) {
      int4 o = make_int4(excl, excl + t0, excl + t1, excl + t2);
      *(int4*)(row_ptr + idx) = o;
    }
    carry += wsum[15];
    __syncthreads();
  }
  if (tid == 0) row_ptr[NNODE] = carry;
}

__global__ void scatter_kernel(const int* __restrict__ ei, const int* __restrict__ flag,
                               const int* __restrict__ row_ptr, int* __restrict__ cursor,
                               int* __restrict__ src_sorted, int* __restrict__ pos) {
  int e = blockIdx.x * blockDim.x + threadIdx.x;
  if (e < NEDGE) {
    int w = flag[0];
    int d = load_idx(ei, e, 1, w);
    int s = load_idx(ei, e, 0, w);
    int p = row_ptr[d] + atomicAdd(&cursor[d], 1);
    src_sorted[p] = s;
    pos[e] = p;
  }
}

// ---------------------------------------------------------------- v1,v2 = fold(We, a_e) both layers
__global__ void prep_kernel(const float* __restrict__ We1, const float* __restrict__ ae1,
                            const float* __restrict__ We2, const float* __restrict__ ae2,
                            float* __restrict__ v1, float* __restrict__ v2) {
  int t = threadIdx.x;  // 128 threads
  int layer = t >> 6, u = t & 63;
  int d = u >> 2, h = u & 3;
  const float* We = layer ? We2 : We1;
  const float* ae = layer ? ae2 : ae1;
  float s = 0.f;
  for (int c = 0; c < CHv; c++) s += We[(size_t)d * HCv + h * CHv + c] * ae[h * CHv + c];
  (layer ? v2 : v1)[d * 4 + h] = s;
}

// ---------------------------------------------------------------- al_e (both layers, perm order) + mean partials
__global__ void ale_both_kernel(const float* __restrict__ ea, const int* __restrict__ pos,
                                const float* __restrict__ v1, const float* __restrict__ v2,
                                float* __restrict__ al1, float* __restrict__ al2,
                                float* __restrict__ partials) {
  __shared__ float sv1[64], sv2[64];
  if (threadIdx.x < 64) sv1[threadIdx.x] = v1[threadIdx.x];
  else if (threadIdx.x < 128) sv2[threadIdx.x - 64] = v2[threadIdx.x - 64];
  __syncthreads();
  float acc[EDv];
#pragma unroll
  for (int d = 0; d < EDv; d++) acc[d] = 0.f;
  int stride = gridDim.x * blockDim.x;
  for (int e = blockIdx.x * blockDim.x + threadIdx.x; e < NEDGE; e += stride) {
    const float4* pr = (const float4*)(ea + (size_t)e * EDv);
    float row[16];
    *(float4*)&row[0] = pr[0]; *(float4*)&row[4] = pr[1];
    *(float4*)&row[8] = pr[2]; *(float4*)&row[12] = pr[3];
    float a0 = 0, a1 = 0, a2 = 0, a3 = 0;
    float b0 = 0, b1 = 0, b2 = 0, b3 = 0;
#pragma unroll
    for (int d = 0; d < 16; d++) {
      acc[d] += row[d];
      a0 += row[d] * sv1[d * 4 + 0];
      a1 += row[d] * sv1[d * 4 + 1];
      a2 += row[d] * sv1[d * 4 + 2];
      a3 += row[d] * sv1[d * 4 + 3];
      b0 += row[d] * sv2[d * 4 + 0];
      b1 += row[d] * sv2[d * 4 + 1];
      b2 += row[d] * sv2[d * 4 + 2];
      b3 += row[d] * sv2[d * 4 + 3];
    }
    int p = pos[e];
    ((float4*)al1)[p] = make_float4(a0, a1, a2, a3);
    ((float4*)al2)[p] = make_float4(b0, b1, b2, b3);
  }
  __shared__ float red[4][EDv];
  int wid = threadIdx.x >> 6, lane = threadIdx.x & 63;
#pragma unroll
  for (int d = 0; d < EDv; d++) {
    float v = acc[d];
    for (int off = 32; off; off >>= 1) v += __shfl_down(v, off, 64);
    if (lane == 0) red[wid][d] = v;
  }
  __syncthreads();
  if (threadIdx.x < EDv) {
    float v = red[0][threadIdx.x] + red[1][threadIdx.x] + red[2][threadIdx.x] + red[3][threadIdx.x];
    partials[blockIdx.x * EDv + threadIdx.x] = v;
  }
}

// ---------------------------------------------------------------- fold mean + loop_al_e for both layers
__global__ void fold_kernel(const float* __restrict__ partials,
                            const float* __restrict__ v1, const float* __restrict__ v2,
                            float* __restrict__ loop1, float* __restrict__ loop2) {
  int tid = threadIdx.x;
  int d = tid & 15, r0 = tid >> 4;
  float v = 0.f;
  for (int r = r0; r < MEANBLK; r += 16) v += partials[r * EDv + d];
  __shared__ float buf[256];
  __shared__ float ms[16];
  buf[tid] = v;
  __syncthreads();
  if (r0 < 8) buf[tid] += buf[tid + 128];
  __syncthreads();
  if (r0 < 4) buf[tid] += buf[tid + 64];
  __syncthreads();
  if (r0 < 2) buf[tid] += buf[tid + 32];
  __syncthreads();
  if (r0 == 0) ms[d] = (buf[tid] + buf[tid + 16]) * (1.0f / NEDGE);
  __syncthreads();
  if (tid < 8) {
    const float* vv = (tid >> 2) ? v2 : v1;
    int h = tid & 3;
    float a = 0.f;
    for (int d2 = 0; d2 < EDv; d2++) a += ms[d2] * vv[d2 * 4 + h];
    ((tid >> 2) ? loop2 : loop1)[h] = a;
  }
}

// ---------------------------------------------------------------- conv x->bf16 + both weight transposes
__global__ void convwt_kernel(const float* __restrict__ x, const float* __restrict__ W1,
                              const float* __restrict__ W2, ushort* __restrict__ xb,
                              ushort* __restrict__ Bt1, ushort* __restrict__ Bt2) {
  int i = blockIdx.x * 256 + threadIdx.x;
  if (i < CONVN) {
    float4 v = ((const float4*)x)[i];
    ushort4 o;
    o.x = f2b(v.x); o.y = f2b(v.y); o.z = f2b(v.z); o.w = f2b(v.w);
    ((ushort4*)xb)[i] = o;
  } else if (i < CONVN + DINv * HCv) {
    int idx = i - CONVN;
    int k = idx >> 9, n = idx & (HCv - 1);
    Bt1[(size_t)n * DINv + k] = f2b(W1[idx]);
  } else if (i < CONVN + DINv * HCv + HCv * HCv) {
    int idx = i - CONVN - DINv * HCv;
    int k = idx >> 9, n = idx & (HCv - 1);
    Bt2[(size_t)n * HCv + k] = f2b(W2[idx]);
  }
}

// ---------------------------------------------------------------- bf16 MFMA GEMM (BK=64) + fused rowdots
__global__ __launch_bounds__(256) void gemm_mfma_kernel(const ushort* __restrict__ A,
                                                        const ushort* __restrict__ Bt,
                                                        ushort* __restrict__ C, int M, int K,
                                                        const float* __restrict__ a_src,
                                                        const float* __restrict__ a_dst,
                                                        float* __restrict__ al_src,
                                                        float* __restrict__ al_dst) {
  __shared__ ushort As[8][128][8];  // 16 KB
  __shared__ ushort Bs[8][128][8];  // 16 KB
  __shared__ float ssa[128], ssd[128];
  __shared__ float rsum[2][128][2];
  int tid = threadIdx.x;
  int wid = tid >> 6, lane = tid & 63;

  // bijective XCD-chunk swizzle over gridDim.x * gridDim.y blocks (x fastest)
  int nblk = gridDim.x * gridDim.y;
  int j = blockIdx.y * gridDim.x + blockIdx.x;
  int q = nblk >> 3, rem = nblk & 7;
  int xcd = j & 7, idx = j >> 3;
  int d = (xcd < rem) ? xcd * (q + 1) + idx : rem * (q + 1) + (xcd - rem) * q + idx;
  int rb = (d >> 2) * 128, cb = (d & 3) * 128;
  int hblk = cb >> 7;

  int wm = (wid >> 1) * 64, wn = (wid & 1) * 64;
  int lr = lane & 15, lq = lane >> 4;

  if (tid < 128) { ssa[tid] = a_src[cb + tid]; ssd[tid] = a_dst[cb + tid]; }

  f32x4 acc[4][4];
#pragma unroll
  for (int i = 0; i < 4; i++)
#pragma unroll
    for (int jx = 0; jx < 4; jx++) acc[i][jx] = (f32x4){0.f, 0.f, 0.f, 0.f};

  ushort* AsF = &As[0][0][0];
  ushort* BsF = &Bs[0][0][0];

  for (int k0 = 0; k0 < K; k0 += 64) {
#pragma unroll
    for (int s = 0; s < 4; s++) {
      int c = s * 256 + tid;        // chunk = kq*128 + m, kq in 0..7
      int kq = c >> 7, m = c & 127;
      int row = rb + m; if (row >= M) row = M - 1;
      const ushort* gA = A + (size_t)row * K + k0 + kq * 8;
      __builtin_amdgcn_global_load_lds((glb_u32*)gA, (lds_u32*)(AsF + (size_t)c * 8), 16, 0, 0);
    }
#pragma unroll
    for (int s = 0; s < 4; s++) {
      int c = s * 256 + tid;        // chunk = kq*128 + n
      int kq = c >> 7, n = c & 127;
      const ushort* gB = Bt + (size_t)(cb + n) * K + k0 + kq * 8;
      __builtin_amdgcn_global_load_lds((glb_u32*)gB, (lds_u32*)(BsF + (size_t)c * 8), 16, 0, 0);
    }
    __syncthreads();
#pragma unroll
    for (int hh = 0; hh < 2; hh++) {
      bf16x8 af[4], bfr[4];
#pragma unroll
      for (int i = 0; i < 4; i++) {
        af[i]  = *(const bf16x8*)&As[hh * 4 + lq][wm + i * 16 + lr][0];
        bfr[i] = *(const bf16x8*)&Bs[hh * 4 + lq][wn + i * 16 + lr][0];
      }
#pragma unroll
      for (int i = 0; i < 4; i++)
#pragma unroll
        for (int jx = 0; jx < 4; jx++)
          acc[i][jx] = __builtin_amdgcn_mfma_f32_16x16x32_bf16(af[i], bfr[jx], acc[i][jx], 0, 0, 0);
    }
    __syncthreads();
  }

  // C store (bf16)
#pragma unroll
  for (int i = 0; i < 4; i++) {
    int rbase = rb + wm + i * 16 + lq * 4;
#pragma unroll
    for (int jx = 0; jx < 4; jx++) {
      int col = cb + wn + jx * 16 + lr;
#pragma unroll
      for (int r = 0; r < 4; r++) {
        int row = rbase + r;
        if (row < M) C[(size_t)row * HCv + col] = f2b(acc[i][jx][r]);
      }
    }
  }

  // fused rowdots epilogue
  float sa[4], sd[4];
#pragma unroll
  for (int jx = 0; jx < 4; jx++) {
    int c = wn + jx * 16 + lr;
    sa[jx] = ssa[c]; sd[jx] = ssd[c];
  }
#pragma unroll
  for (int i = 0; i < 4; i++) {
#pragma unroll
    for (int r = 0; r < 4; r++) {
      float s1 = 0.f, s2 = 0.f;
#pragma unroll
      for (int jx = 0; jx < 4; jx++) {
        s1 = fmaf(acc[i][jx][r], sa[jx], s1);
        s2 = fmaf(acc[i][jx][r], sd[jx], s2);
      }
#pragma unroll
      for (int off = 1; off < 16; off <<= 1) {
        s1 += __shfl_xor(s1, off, 16);
        s2 += __shfl_xor(s2, off, 16);
      }
      if (lr == 0) {
        int row = wm + i * 16 + lq * 4 + r;
        rsum[0][row][wn >> 6] = s1;
        rsum[1][row][wn >> 6] = s2;
      }
    }
  }
  __syncthreads();
  if (tid < 128) {
    int row = rb + tid;
    if (row < M) {
      al_src[(size_t)row * 4 + hblk] = rsum[0][tid][0] + rsum[0][tid][1];
      al_dst[(size_t)row * 4 + hblk] = rsum[1][tid][0] + rsum[1][tid][1];
    }
  }
}

// ---------------------------------------------------------------- per-node softmax + aggregate
// ONE WAVE PER NODE, no max pass. alpha computed inline:
// a = al_src[src] (L2-resident gather) + al_e_s[p] (sequential) + al_dst[n].
__device__ __forceinline__ void fma8(float* acc, float w, uint4 u) {
  acc[0] = fmaf(w, blo(u.x), acc[0]);
  acc[1] = fmaf(w, bhi(u.x), acc[1]);
  acc[2] = fmaf(w, blo(u.y), acc[2]);
  acc[3] = fmaf(w, bhi(u.y), acc[3]);
  acc[4] = fmaf(w, blo(u.z), acc[4]);
  acc[5] = fmaf(w, bhi(u.z), acc[5]);
  acc[6] = fmaf(w, blo(u.w), acc[6]);
  acc[7] = fmaf(w, bhi(u.w), acc[7]);
}

__global__ __launch_bounds__(256) void node_kernel(
    const ushort* __restrict__ hb, const float* __restrict__ al_src,
    const float* __restrict__ al_dst, const float* __restrict__ al_e,
    const float* __restrict__ loop_al_e, const int* __restrict__ row_ptr,
    const int* __restrict__ src_sorted, const float* __restrict__ bias,
    float* __restrict__ outf, ushort* __restrict__ outb) {
  int wid = threadIdx.x >> 6, lane = threadIdx.x & 63;
  int n = blockIdx.x * 4 + wid;
  if (n >= NNODE) return;
  int base = row_ptr[n];
  int deg = row_ptr[n + 1] - base;
  int h = lane >> 4;     // head of this lane's 8 columns
  int jj = lane & 15;    // edge slot within a 16-edge chunk

  float aldh = al_dst[(size_t)n * 4 + h];
  float a0 = al_src[(size_t)n * 4 + h] + aldh + loop_al_e[h];
  float alph = a0 > 0.f ? a0 : SLOPEv * a0;
  float wl = __expf(alph);

  // self row, issued early
  uint4 uself = *((const uint4*)(hb + ((size_t)n << 9)) + lane);

  float acc[8];
#pragma unroll
  for (int q = 0; q < 8; q++) acc[q] = 0.f;
  float den = 0.f;

  for (int cs = 0; cs < deg; cs += 16) {
    int cl = min(16, deg - cs);
    float w = 0.f;
    int sv = 0;
    if (jj < cl) {
      int p = base + cs + jj;
      sv = src_sorted[p];
      float a = al_src[(size_t)sv * 4 + h] + al_e[(size_t)p * 4 + h] + aldh;
      a = a > 0.f ? a : SLOPEv * a;
      w = __expf(a);
      den += w;
    }
    int cl4 = (cl + 3) & ~3;   // lanes j>=cl have w=0, sv=0 (harmless hot row-0 load)
    for (int j0 = 0; j0 < cl4; j0 += 4) {
      int s0 = __shfl(sv, j0 + 0, 16);
      int s1 = __shfl(sv, j0 + 1, 16);
      int s2 = __shfl(sv, j0 + 2, 16);
      int s3 = __shfl(sv, j0 + 3, 16);
      float w0 = __shfl(w, j0 + 0, 16);
      float w1 = __shfl(w, j0 + 1, 16);
      float w2 = __shfl(w, j0 + 2, 16);
      float w3 = __shfl(w, j0 + 3, 16);
      uint4 u0 = *((const uint4*)(hb + ((size_t)s0 << 9)) + lane);
      uint4 u1 = *((const uint4*)(hb + ((size_t)s1 << 9)) + lane);
      uint4 u2 = *((const uint4*)(hb + ((size_t)s2 << 9)) + lane);
      uint4 u3 = *((const uint4*)(hb + ((size_t)s3 << 9)) + lane);
      fma8(acc, w0, u0);
      fma8(acc, w1, u1);
      fma8(acc, w2, u2);
      fma8(acc, w3, u3);
    }
  }

  // self loop
  fma8(acc, wl, uself);

  // denominator: reduce over the 16 j-slots within each head group
#pragma unroll
  for (int off = 8; off; off >>= 1) den += __shfl_xor(den, off, 16);
  den += wl;
  float rden = 1.f / (den + 1e-16f);

  // epilogue
  const float4* bp = (const float4*)(bias + lane * 8);
  float4 b0 = bp[0], b1 = bp[1];
  float bv[8] = {b0.x, b0.y, b0.z, b0.w, b1.x, b1.y, b1.z, b1.w};
  float r[8];
#pragma unroll
  for (int q = 0; q < 8; q++) {
    float t = acc[q] * rden + bv[q];
    r[q] = t > 0.f ? t : expm1f(t);
  }
  if (outf) {
    float4* op = (float4*)(outf + (size_t)n * HCv + lane * 8);
    op[0] = make_float4(r[0], r[1], r[2], r[3]);
    op[1] = make_float4(r[4], r[5], r[6], r[7]);
  }
  if (outb) {
    uint4 o;
    o.x = (unsigned)f2b(r[0]) | ((unsigned)f2b(r[1]) << 16);
    o.y = (unsigned)f2b(r[2]) | ((unsigned)f2b(r[3]) << 16);
    o.z = (unsigned)f2b(r[4]) | ((unsigned)f2b(r[5]) << 16);
    o.w = (unsigned)f2b(r[6]) | ((unsigned)f2b(r[7]) << 16);
    ((uint4*)(outb + (size_t)n * HCv))[lane] = o;
  }
}

// ---------------------------------------------------------------- launch
static inline char* take(char*& p, size_t bytes) {
  char* r = p;
  p += (bytes + 255) & ~(size_t)255;
  return r;
}

extern "C" void kernel_launch(void* const* d_in, const int* in_sizes, int n_in,
                              void* d_out, int out_size, void* d_ws, size_t ws_size,
                              hipStream_t stream) {
  (void)in_sizes; (void)n_in; (void)out_size; (void)ws_size;
  const float* x   = (const float*)d_in[0];
  const int*   ei  = (const int*)d_in[1];
  const float* ea  = (const float*)d_in[2];
  const float* W1  = (const float*)d_in[3];
  const float* as1 = (const float*)d_in[4];
  const float* ad1 = (const float*)d_in[5];
  const float* We1 = (const float*)d_in[6];
  const float* ae1 = (const float*)d_in[7];
  const float* b1  = (const float*)d_in[8];
  const float* W2  = (const float*)d_in[9];
  const float* as2 = (const float*)d_in[10];
  const float* ad2 = (const float*)d_in[11];
  const float* We2 = (const float*)d_in[12];
  const float* ae2 = (const float*)d_in[13];
  const float* b2  = (const float*)d_in[14];
  float* out = (float*)d_out;

  char* p = (char*)d_ws;
  ushort* hb        = (ushort*)take(p, (size_t)NNODE * HCv * 2);
  float* al_src     = (float*)take(p, (size_t)NNODE * 4 * 4);
  float* al_dst     = (float*)take(p, (size_t)NNODE * 4 * 4);
  float* ale1       = (float*)take(p, (size_t)NEDGE * 4 * 4);
  float* ale2       = (float*)take(p, (size_t)NEDGE * 4 * 4);
  int*   src_sorted = (int*)take(p, (size_t)NEDGE * 4);
  int*   pos        = (int*)take(p, (size_t)NEDGE * 4);
  int*   row_ptr    = (int*)take(p, (size_t)(NNODE + 1) * 4);
  float* partials   = (float*)take(p, (size_t)MEANBLK * EDv * 4);
  ushort* Bt1       = (ushort*)take(p, (size_t)HCv * DINv * 2);
  ushort* Bt2       = (ushort*)take(p, (size_t)HCv * HCv * 2);
  char* zero_begin = p;
  int*   deg        = (int*)take(p, (size_t)NNODE * 4);
  int*   cursor     = (int*)take(p, (size_t)NNODE * 4);
  size_t zero_len = (size_t)(p - zero_begin);
  float* v1         = (float*)take(p, 64 * 4);
  float* v2         = (float*)take(p, 64 * 4);
  float* loop1      = (float*)take(p, 4 * 4);
  float* loop2      = (float*)take(p, 4 * 4);
  int*   flag       = (int*)take(p, 4);

  // scratch carved out of d_out (102.4 MB): xb dead after layer-1 gemm,
  // h1b dead after layer-2 gemm; final out written only by the last node_kernel.
  ushort* xb  = (ushort*)d_out;                                       // 12.8 MB
  ushort* h1b = (ushort*)((char*)d_out + (size_t)16 * 1024 * 1024);   // 51.2 MB

  hipMemsetAsync(zero_begin, 0, zero_len, stream);

  detect_kernel<<<1, 256, 0, stream>>>(ei, flag);
  count_kernel<<<(NEDGE + 255) / 256, 256, 0, stream>>>(ei, flag, deg);
  scan_kernel<<<1, 1024, 0, stream>>>(deg, row_ptr);
  scatter_kernel<<<(NEDGE + 255) / 256, 256, 0, stream>>>(ei, flag, row_ptr, cursor,
                                                          src_sorted, pos);
  prep_kernel<<<1, 128, 0, stream>>>(We1, ae1, We2, ae2, v1, v2);
  convwt_kernel<<<(CONVN + DINv * HCv + HCv * HCv + 255) / 256, 256, 0, stream>>>(
      x, W1, W2, xb, Bt1, Bt2);
  ale_both_kernel<<<MEANBLK, 256, 0, stream>>>(ea, pos, v1, v2, ale1, ale2, partials);
  fold_kernel<<<1, 256, 0, stream>>>(partials, v1, v2, loop1, loop2);

  // ---- layer 1
  gemm_mfma_kernel<<<dim3(HCv / 128, (NNODE + 127) / 128), 256, 0, stream>>>(
      xb, Bt1, hb, NNODE, DINv, as1, ad1, al_src, al_dst);
  node_kernel<<<(NNODE + 3) / 4, 256, 0, stream>>>(hb, al_src, al_dst, ale1, loop1, row_ptr,
                                                   src_sorted, b1, (float*)nullptr, h1b);

  // ---- layer 2
  gemm_mfma_kernel<<<dim3(HCv / 128, (NNODE + 127) / 128), 256, 0, stream>>>(
      h1b, Bt2, hb, NNODE, HCv, as2, ad2, al_src, al_dst);
  node_kernel<<<(NNODE + 3) / 4, 256, 0, stream>>>(hb, al_src, al_dst, ale2, loop2, row_ptr,
                                                   src_sorted, b2, out, (ushort*)nullptr);
}

// Round 6
// 720.793 us; speedup vs baseline: 1.0695x; 1.0695x over previous
//
#include <hip/hip_runtime.h>
#include <math.h>

#define NNODE 50000
#define NEDGE 800000
#define DINv  128
#define EDv   16
#define NHv   4
#define CHv   128
#define HCv   512
#define SLOPEv 0.2f
#define MEANBLK 512
#define CONVN (NNODE * DINv / 4)

typedef __attribute__((ext_vector_type(8))) short bf16x8;
typedef __attribute__((ext_vector_type(4))) float f32x4;
typedef __attribute__((address_space(3))) unsigned lds_u32;
typedef const __attribute__((address_space(1))) unsigned glb_u32;

__device__ __forceinline__ ushort f2b(float f) {
  unsigned u = __float_as_uint(f);
  u += 0x7FFF + ((u >> 16) & 1);
  return (ushort)(u >> 16);
}
__device__ __forceinline__ float blo(unsigned u) { return __uint_as_float(u << 16); }
__device__ __forceinline__ float bhi(unsigned u) { return __uint_as_float(u & 0xffff0000u); }

// ---------------------------------------------------------------- CSR build
__global__ void detect_kernel(const int* __restrict__ ei, int* __restrict__ flag) {
  __shared__ int bad;
  if (threadIdx.x == 0) bad = 0;
  __syncthreads();
  for (int i = threadIdx.x; i < 2048; i += 256)
    if (ei[2 * i + 1] != 0) bad = 1;
  __syncthreads();
  if (threadIdx.x == 0) flag[0] = bad ? 0 : 1;
}

__device__ __forceinline__ int load_idx(const int* __restrict__ ei, int e, int row, int wide) {
  if (wide) return ei[2 * ((size_t)row * NEDGE + e)];
  return ei[(size_t)row * NEDGE + e];
}

__global__ void count_kernel(const int* __restrict__ ei, const int* __restrict__ flag,
                             int* __restrict__ deg) {
  int e = blockIdx.x * blockDim.x + threadIdx.x;
  if (e < NEDGE) {
    int w = flag[0];
    atomicAdd(&deg[load_idx(ei, e, 1, w)], 1);
  }
}

// shfl-based single-block scan, 4 elements/thread (13 serial chunks)
__global__ __launch_bounds__(1024) void scan_kernel(const int* __restrict__ deg,
                                                    int* __restrict__ row_ptr) {
  __shared__ int wsum[16];
  int tid = threadIdx.x;
  int wid = tid >> 6, lane = tid & 63;
  int carry = 0;
  for (int base = 0; base < NNODE; base += 4096) {
    int idx = base + tid * 4;
    int4 x = make_int4(0, 0, 0, 0);
    if (idx < NNODE) x = *(const int4*)(deg + idx);   // NNODE % 4 == 0
    int t0 = x.x, t1 = t0 + x.y, t2 = t1 + x.z, t3 = t2 + x.w;
    int v = t3;
#pragma unroll
    for (int off = 1; off < 64; off <<= 1) {
      int t = __shfl_up(v, off, 64);
      if (lane >= off) v += t;
    }
    if (lane == 63) wsum[wid] = v;
    __syncthreads();
    if (wid == 0) {
      int s = (lane < 16) ? wsum[lane] : 0;
#pragma unroll
      for (int off = 1; off < 16; off <<= 1) {
        int t = __shfl_up(s, off, 64);
        if (lane >= off) s += t;
      }
      if (lane < 16) wsum[lane] = s;
    }
    __syncthreads();
    int woff = wid ? wsum[wid - 1] : 0;
    int excl = carry + woff + v - t3;
    if (idx < NNODE) {
      int4 o = make_int4(excl, excl + t0, excl + t1, excl + t2);
      *(int4*)(row_ptr + idx) = o;
    }
    carry += wsum[15];
    __syncthreads();
  }
  if (tid == 0) row_ptr[NNODE] = carry;
}

__global__ void scatter_kernel(const int* __restrict__ ei, const int* __restrict__ flag,
                               const int* __restrict__ row_ptr, int* __restrict__ cursor,
                               int* __restrict__ src_sorted, int* __restrict__ eid_sorted) {
  int e = blockIdx.x * blockDim.x + threadIdx.x;
  if (e < NEDGE) {
    int w = flag[0];
    int d = load_idx(ei, e, 1, w);
    int s = load_idx(ei, e, 0, w);
    int p = row_ptr[d] + atomicAdd(&cursor[d], 1);
    src_sorted[p] = s;
    eid_sorted[p] = e;
  }
}

// ---------------------------------------------------------------- v1,v2 = fold(We, a_e) both layers
__global__ void prep_kernel(const float* __restrict__ We1, const float* __restrict__ ae1,
                            const float* __restrict__ We2, const float* __restrict__ ae2,
                            float* __restrict__ v1, float* __restrict__ v2) {
  int t = threadIdx.x;  // 128 threads
  int layer = t >> 6, u = t & 63;
  int d = u >> 2, h = u & 3;
  const float* We = layer ? We2 : We1;
  const float* ae = layer ? ae2 : ae1;
  float s = 0.f;
  for (int c = 0; c < CHv; c++) s += We[(size_t)d * HCv + h * CHv + c] * ae[h * CHv + c];
  (layer ? v2 : v1)[d * 4 + h] = s;
}

// ---------------------------------------------------------------- mean(edge_features) (also warms ea in L3)
__global__ void mean_part_kernel(const float* __restrict__ ea, float* __restrict__ partials) {
  float acc[EDv];
#pragma unroll
  for (int d = 0; d < EDv; d++) acc[d] = 0.f;
  int stride = gridDim.x * blockDim.x;
  for (int r = blockIdx.x * blockDim.x + threadIdx.x; r < NEDGE; r += stride) {
    const float4* p = (const float4*)(ea + (size_t)r * EDv);
#pragma unroll
    for (int q = 0; q < 4; q++) {
      float4 v = p[q];
      acc[q * 4 + 0] += v.x; acc[q * 4 + 1] += v.y;
      acc[q * 4 + 2] += v.z; acc[q * 4 + 3] += v.w;
    }
  }
  __shared__ float red[4][EDv];
  int wid = threadIdx.x >> 6, lane = threadIdx.x & 63;
#pragma unroll
  for (int d = 0; d < EDv; d++) {
    float v = acc[d];
    for (int off = 32; off; off >>= 1) v += __shfl_down(v, off, 64);
    if (lane == 0) red[wid][d] = v;
  }
  __syncthreads();
  if (threadIdx.x < EDv) {
    float v = red[0][threadIdx.x] + red[1][threadIdx.x] + red[2][threadIdx.x] + red[3][threadIdx.x];
    partials[blockIdx.x * EDv + threadIdx.x] = v;
  }
}

// ---------------------------------------------------------------- fold mean + loop_al_e for both layers
__global__ void fold_kernel(const float* __restrict__ partials,
                            const float* __restrict__ v1, const float* __restrict__ v2,
                            float* __restrict__ loop1, float* __restrict__ loop2) {
  int tid = threadIdx.x;
  int d = tid & 15, r0 = tid >> 4;
  float v = 0.f;
  for (int r = r0; r < MEANBLK; r += 16) v += partials[r * EDv + d];
  __shared__ float buf[256];
  __shared__ float ms[16];
  buf[tid] = v;
  __syncthreads();
  if (r0 < 8) buf[tid] += buf[tid + 128];
  __syncthreads();
  if (r0 < 4) buf[tid] += buf[tid + 64];
  __syncthreads();
  if (r0 < 2) buf[tid] += buf[tid + 32];
  __syncthreads();
  if (r0 == 0) ms[d] = (buf[tid] + buf[tid + 16]) * (1.0f / NEDGE);
  __syncthreads();
  if (tid < 8) {
    const float* vv = (tid >> 2) ? v2 : v1;
    int h = tid & 3;
    float a = 0.f;
    for (int d2 = 0; d2 < EDv; d2++) a += ms[d2] * vv[d2 * 4 + h];
    ((tid >> 2) ? loop2 : loop1)[h] = a;
  }
}

// ---------------------------------------------------------------- conv x->bf16 + both weight transposes
__global__ void convwt_kernel(const float* __restrict__ x, const float* __restrict__ W1,
                              const float* __restrict__ W2, ushort* __restrict__ xb,
                              ushort* __restrict__ Bt1, ushort* __restrict__ Bt2) {
  int i = blockIdx.x * 256 + threadIdx.x;
  if (i < CONVN) {
    float4 v = ((const float4*)x)[i];
    ushort4 o;
    o.x = f2b(v.x); o.y = f2b(v.y); o.z = f2b(v.z); o.w = f2b(v.w);
    ((ushort4*)xb)[i] = o;
  } else if (i < CONVN + DINv * HCv) {
    int idx = i - CONVN;
    int k = idx >> 9, n = idx & (HCv - 1);
    Bt1[(size_t)n * DINv + k] = f2b(W1[idx]);
  } else if (i < CONVN + DINv * HCv + HCv * HCv) {
    int idx = i - CONVN - DINv * HCv;
    int k = idx >> 9, n = idx & (HCv - 1);
    Bt2[(size_t)n * HCv + k] = f2b(W2[idx]);
  }
}

// ---------------------------------------------------------------- ap1 = al_src1[s] + ea[e]@v1 ; ale2s = ea[e]@v2
// Gather-based (64B ea row = one cache line, L3-warm); sequential writes.
__global__ void apre1_kernel(const int* __restrict__ src_sorted, const int* __restrict__ eid_sorted,
                             const float* __restrict__ ea, const float* __restrict__ al_src,
                             const float* __restrict__ v1, const float* __restrict__ v2,
                             float* __restrict__ ap1, float* __restrict__ ale2s) {
  __shared__ float sv1[64], sv2[64];
  if (threadIdx.x < 64) sv1[threadIdx.x] = v1[threadIdx.x];
  else if (threadIdx.x < 128) sv2[threadIdx.x - 64] = v2[threadIdx.x - 64];
  __syncthreads();
  int p = blockIdx.x * 256 + threadIdx.x;
  if (p >= NEDGE) return;
  int s = src_sorted[p];
  int e = eid_sorted[p];
  const float4* pr = (const float4*)(ea + (size_t)e * EDv);
  float row[16];
  *(float4*)&row[0] = pr[0]; *(float4*)&row[4] = pr[1];
  *(float4*)&row[8] = pr[2]; *(float4*)&row[12] = pr[3];
  float a0 = 0, a1 = 0, a2 = 0, a3 = 0;
  float b0 = 0, b1 = 0, b2 = 0, b3 = 0;
#pragma unroll
  for (int d = 0; d < 16; d++) {
    a0 += row[d] * sv1[d * 4 + 0];
    a1 += row[d] * sv1[d * 4 + 1];
    a2 += row[d] * sv1[d * 4 + 2];
    a3 += row[d] * sv1[d * 4 + 3];
    b0 += row[d] * sv2[d * 4 + 0];
    b1 += row[d] * sv2[d * 4 + 1];
    b2 += row[d] * sv2[d * 4 + 2];
    b3 += row[d] * sv2[d * 4 + 3];
  }
  float4 as = ((const float4*)al_src)[s];
  ((float4*)ap1)[p] = make_float4(as.x + a0, as.y + a1, as.z + a2, as.w + a3);
  ((float4*)ale2s)[p] = make_float4(b0, b1, b2, b3);
}

// ---------------------------------------------------------------- ap2 = al_src2[s] + ale2s (seq)
__global__ void apre2_kernel(const int* __restrict__ src_sorted, const float* __restrict__ ale2s,
                             const float* __restrict__ al_src, float* __restrict__ ap2) {
  int p = blockIdx.x * 256 + threadIdx.x;
  if (p >= NEDGE) return;
  int s = src_sorted[p];
  float4 a = ((const float4*)al_src)[s];
  float4 b = ((const float4*)ale2s)[p];
  ((float4*)ap2)[p] = make_float4(a.x + b.x, a.y + b.y, a.z + b.z, a.w + b.w);
}

// ---------------------------------------------------------------- bf16 MFMA GEMM (BK=64) + fused rowdots
__global__ __launch_bounds__(256) void gemm_mfma_kernel(const ushort* __restrict__ A,
                                                        const ushort* __restrict__ Bt,
                                                        ushort* __restrict__ C, int M, int K,
                                                        const float* __restrict__ a_src,
                                                        const float* __restrict__ a_dst,
                                                        float* __restrict__ al_src,
                                                        float* __restrict__ al_dst) {
  __shared__ ushort As[8][128][8];  // 16 KB
  __shared__ ushort Bs[8][128][8];  // 16 KB
  __shared__ float ssa[128], ssd[128];
  __shared__ float rsum[2][128][2];
  int tid = threadIdx.x;
  int wid = tid >> 6, lane = tid & 63;

  // bijective XCD-chunk swizzle over gridDim.x * gridDim.y blocks (x fastest)
  int nblk = gridDim.x * gridDim.y;
  int j = blockIdx.y * gridDim.x + blockIdx.x;
  int q = nblk >> 3, rem = nblk & 7;
  int xcd = j & 7, idx = j >> 3;
  int d = (xcd < rem) ? xcd * (q + 1) + idx : rem * (q + 1) + (xcd - rem) * q + idx;
  int rb = (d >> 2) * 128, cb = (d & 3) * 128;
  int hblk = cb >> 7;

  int wm = (wid >> 1) * 64, wn = (wid & 1) * 64;
  int lr = lane & 15, lq = lane >> 4;

  if (tid < 128) { ssa[tid] = a_src[cb + tid]; ssd[tid] = a_dst[cb + tid]; }

  f32x4 acc[4][4];
#pragma unroll
  for (int i = 0; i < 4; i++)
#pragma unroll
    for (int jx = 0; jx < 4; jx++) acc[i][jx] = (f32x4){0.f, 0.f, 0.f, 0.f};

  ushort* AsF = &As[0][0][0];
  ushort* BsF = &Bs[0][0][0];

  for (int k0 = 0; k0 < K; k0 += 64) {
#pragma unroll
    for (int s = 0; s < 4; s++) {
      int c = s * 256 + tid;        // chunk = kq*128 + m, kq in 0..7
      int kq = c >> 7, m = c & 127;
      int row = rb + m; if (row >= M) row = M - 1;
      const ushort* gA = A + (size_t)row * K + k0 + kq * 8;
      __builtin_amdgcn_global_load_lds((glb_u32*)gA, (lds_u32*)(AsF + (size_t)c * 8), 16, 0, 0);
    }
#pragma unroll
    for (int s = 0; s < 4; s++) {
      int c = s * 256 + tid;        // chunk = kq*128 + n
      int kq = c >> 7, n = c & 127;
      const ushort* gB = Bt + (size_t)(cb + n) * K + k0 + kq * 8;
      __builtin_amdgcn_global_load_lds((glb_u32*)gB, (lds_u32*)(BsF + (size_t)c * 8), 16, 0, 0);
    }
    __syncthreads();
#pragma unroll
    for (int hh = 0; hh < 2; hh++) {
      bf16x8 af[4], bfr[4];
#pragma unroll
      for (int i = 0; i < 4; i++) {
        af[i]  = *(const bf16x8*)&As[hh * 4 + lq][wm + i * 16 + lr][0];
        bfr[i] = *(const bf16x8*)&Bs[hh * 4 + lq][wn + i * 16 + lr][0];
      }
#pragma unroll
      for (int i = 0; i < 4; i++)
#pragma unroll
        for (int jx = 0; jx < 4; jx++)
          acc[i][jx] = __builtin_amdgcn_mfma_f32_16x16x32_bf16(af[i], bfr[jx], acc[i][jx], 0, 0, 0);
    }
    __syncthreads();
  }

  // C store (bf16)
#pragma unroll
  for (int i = 0; i < 4; i++) {
    int rbase = rb + wm + i * 16 + lq * 4;
#pragma unroll
    for (int jx = 0; jx < 4; jx++) {
      int col = cb + wn + jx * 16 + lr;
#pragma unroll
      for (int r = 0; r < 4; r++) {
        int row = rbase + r;
        if (row < M) C[(size_t)row * HCv + col] = f2b(acc[i][jx][r]);
      }
    }
  }

  // fused rowdots epilogue
  float sa[4], sd[4];
#pragma unroll
  for (int jx = 0; jx < 4; jx++) {
    int c = wn + jx * 16 + lr;
    sa[jx] = ssa[c]; sd[jx] = ssd[c];
  }
#pragma unroll
  for (int i = 0; i < 4; i++) {
#pragma unroll
    for (int r = 0; r < 4; r++) {
      float s1 = 0.f, s2 = 0.f;
#pragma unroll
      for (int jx = 0; jx < 4; jx++) {
        s1 = fmaf(acc[i][jx][r], sa[jx], s1);
        s2 = fmaf(acc[i][jx][r], sd[jx], s2);
      }
#pragma unroll
      for (int off = 1; off < 16; off <<= 1) {
        s1 += __shfl_xor(s1, off, 16);
        s2 += __shfl_xor(s2, off, 16);
      }
      if (lr == 0) {
        int row = wm + i * 16 + lq * 4 + r;
        rsum[0][row][wn >> 6] = s1;
        rsum[1][row][wn >> 6] = s2;
      }
    }
  }
  __syncthreads();
  if (tid < 128) {
    int row = rb + tid;
    if (row < M) {
      al_src[(size_t)row * 4 + hblk] = rsum[0][tid][0] + rsum[0][tid][1];
      al_dst[(size_t)row * 4 + hblk] = rsum[1][tid][0] + rsum[1][tid][1];
    }
  }
}

// ---------------------------------------------------------------- per-node softmax + aggregate
// ONE WAVE PER NODE, no max pass; sequential ap reads; gather batched 4-deep.
__device__ __forceinline__ void fma8(float* acc, float w, uint4 u) {
  acc[0] = fmaf(w, blo(u.x), acc[0]);
  acc[1] = fmaf(w, bhi(u.x), acc[1]);
  acc[2] = fmaf(w, blo(u.y), acc[2]);
  acc[3] = fmaf(w, bhi(u.y), acc[3]);
  acc[4] = fmaf(w, blo(u.z), acc[4]);
  acc[5] = fmaf(w, bhi(u.z), acc[5]);
  acc[6] = fmaf(w, blo(u.w), acc[6]);
  acc[7] = fmaf(w, bhi(u.w), acc[7]);
}

__global__ __launch_bounds__(256) void node_kernel(
    const ushort* __restrict__ hb, const float* __restrict__ al_src,
    const float* __restrict__ al_dst, const float* __restrict__ ap,
    const float* __restrict__ loop_al_e, const int* __restrict__ row_ptr,
    const int* __restrict__ src_sorted, const float* __restrict__ bias,
    float* __restrict__ outf, ushort* __restrict__ outb) {
  int wid = threadIdx.x >> 6, lane = threadIdx.x & 63;
  int n = blockIdx.x * 4 + wid;
  if (n >= NNODE) return;
  int base = row_ptr[n];
  int deg = row_ptr[n + 1] - base;
  int h = lane >> 4;     // head of this lane's 8 columns
  int jj = lane & 15;    // edge slot within a 16-edge chunk

  float aldh = al_dst[(size_t)n * 4 + h];
  float a0 = al_src[(size_t)n * 4 + h] + aldh + loop_al_e[h];
  float alph = a0 > 0.f ? a0 : SLOPEv * a0;
  float wl = __expf(alph);

  // self row, issued early
  uint4 uself = *((const uint4*)(hb + ((size_t)n << 9)) + lane);

  float acc[8];
#pragma unroll
  for (int q = 0; q < 8; q++) acc[q] = 0.f;
  float den = 0.f;

  for (int cs = 0; cs < deg; cs += 16) {
    int cl = min(16, deg - cs);
    float w = 0.f;
    int sv = 0;
    if (jj < cl) {
      int p = base + cs + jj;
      sv = src_sorted[p];
      float a = ap[(size_t)p * 4 + h] + aldh;
      a = a > 0.f ? a : SLOPEv * a;
      w = __expf(a);
      den += w;
    }
    int cl4 = (cl + 3) & ~3;   // lanes j>=cl have w=0, sv=0 (harmless hot row-0 load)
    for (int j0 = 0; j0 < cl4; j0 += 4) {
      int s0 = __shfl(sv, j0 + 0, 16);
      int s1 = __shfl(sv, j0 + 1, 16);
      int s2 = __shfl(sv, j0 + 2, 16);
      int s3 = __shfl(sv, j0 + 3, 16);
      float w0 = __shfl(w, j0 + 0, 16);
      float w1 = __shfl(w, j0 + 1, 16);
      float w2 = __shfl(w, j0 + 2, 16);
      float w3 = __shfl(w, j0 + 3, 16);
      uint4 u0 = *((const uint4*)(hb + ((size_t)s0 << 9)) + lane);
      uint4 u1 = *((const uint4*)(hb + ((size_t)s1 << 9)) + lane);
      uint4 u2 = *((const uint4*)(hb + ((size_t)s2 << 9)) + lane);
      uint4 u3 = *((const uint4*)(hb + ((size_t)s3 << 9)) + lane);
      fma8(acc, w0, u0);
      fma8(acc, w1, u1);
      fma8(acc, w2, u2);
      fma8(acc, w3, u3);
    }
  }

  // self loop
  fma8(acc, wl, uself);

  // denominator: reduce over the 16 j-slots within each head group
#pragma unroll
  for (int off = 8; off; off >>= 1) den += __shfl_xor(den, off, 16);
  den += wl;
  float rden = 1.f / (den + 1e-16f);

  // epilogue
  const float4* bp = (const float4*)(bias + lane * 8);
  float4 b0 = bp[0], b1 = bp[1];
  float bv[8] = {b0.x, b0.y, b0.z, b0.w, b1.x, b1.y, b1.z, b1.w};
  float r[8];
#pragma unroll
  for (int q = 0; q < 8; q++) {
    float t = acc[q] * rden + bv[q];
    r[q] = t > 0.f ? t : expm1f(t);
  }
  if (outf) {
    float4* op = (float4*)(outf + (size_t)n * HCv + lane * 8);
    op[0] = make_float4(r[0], r[1], r[2], r[3]);
    op[1] = make_float4(r[4], r[5], r[6], r[7]);
  }
  if (outb) {
    uint4 o;
    o.x = (unsigned)f2b(r[0]) | ((unsigned)f2b(r[1]) << 16);
    o.y = (unsigned)f2b(r[2]) | ((unsigned)f2b(r[3]) << 16);
    o.z = (unsigned)f2b(r[4]) | ((unsigned)f2b(r[5]) << 16);
    o.w = (unsigned)f2b(r[6]) | ((unsigned)f2b(r[7]) << 16);
    ((uint4*)(outb + (size_t)n * HCv))[lane] = o;
  }
}

// ---------------------------------------------------------------- launch
static inline char* take(char*& p, size_t bytes) {
  char* r = p;
  p += (bytes + 255) & ~(size_t)255;
  return r;
}

extern "C" void kernel_launch(void* const* d_in, const int* in_sizes, int n_in,
                              void* d_out, int out_size, void* d_ws, size_t ws_size,
                              hipStream_t stream) {
  (void)in_sizes; (void)n_in; (void)out_size; (void)ws_size;
  const float* x   = (const float*)d_in[0];
  const int*   ei  = (const int*)d_in[1];
  const float* ea  = (const float*)d_in[2];
  const float* W1  = (const float*)d_in[3];
  const float* as1 = (const float*)d_in[4];
  const float* ad1 = (const float*)d_in[5];
  const float* We1 = (const float*)d_in[6];
  const float* ae1 = (const float*)d_in[7];
  const float* b1  = (const float*)d_in[8];
  const float* W2  = (const float*)d_in[9];
  const float* as2 = (const float*)d_in[10];
  const float* ad2 = (const float*)d_in[11];
  const float* We2 = (const float*)d_in[12];
  const float* ae2 = (const float*)d_in[13];
  const float* b2  = (const float*)d_in[14];
  float* out = (float*)d_out;

  char* p = (char*)d_ws;
  ushort* hb        = (ushort*)take(p, (size_t)NNODE * HCv * 2);
  float* al_src     = (float*)take(p, (size_t)NNODE * 4 * 4);
  float* al_dst     = (float*)take(p, (size_t)NNODE * 4 * 4);
  float* ap         = (float*)take(p, (size_t)NEDGE * 4 * 4);
  float* ale2s      = (float*)take(p, (size_t)NEDGE * 4 * 4);
  int*   src_sorted = (int*)take(p, (size_t)NEDGE * 4);
  int*   eid_sorted = (int*)take(p, (size_t)NEDGE * 4);
  int*   row_ptr    = (int*)take(p, (size_t)(NNODE + 1) * 4);
  float* partials   = (float*)take(p, (size_t)MEANBLK * EDv * 4);
  ushort* Bt1       = (ushort*)take(p, (size_t)HCv * DINv * 2);
  ushort* Bt2       = (ushort*)take(p, (size_t)HCv * HCv * 2);
  char* zero_begin = p;
  int*   deg        = (int*)take(p, (size_t)NNODE * 4);
  int*   cursor     = (int*)take(p, (size_t)NNODE * 4);
  size_t zero_len = (size_t)(p - zero_begin);
  float* v1         = (float*)take(p, 64 * 4);
  float* v2         = (float*)take(p, 64 * 4);
  float* loop1      = (float*)take(p, 4 * 4);
  float* loop2      = (float*)take(p, 4 * 4);
  int*   flag       = (int*)take(p, 4);

  // scratch carved out of d_out (102.4 MB): xb dead after layer-1 gemm,
  // h1b dead after layer-2 gemm; final out written only by the last node_kernel.
  ushort* xb  = (ushort*)d_out;                                       // 12.8 MB
  ushort* h1b = (ushort*)((char*)d_out + (size_t)16 * 1024 * 1024);   // 51.2 MB

  hipMemsetAsync(zero_begin, 0, zero_len, stream);

  detect_kernel<<<1, 256, 0, stream>>>(ei, flag);
  count_kernel<<<(NEDGE + 255) / 256, 256, 0, stream>>>(ei, flag, deg);
  scan_kernel<<<1, 1024, 0, stream>>>(deg, row_ptr);
  scatter_kernel<<<(NEDGE + 255) / 256, 256, 0, stream>>>(ei, flag, row_ptr, cursor,
                                                          src_sorted, eid_sorted);
  prep_kernel<<<1, 128, 0, stream>>>(We1, ae1, We2, ae2, v1, v2);
  mean_part_kernel<<<MEANBLK, 256, 0, stream>>>(ea, partials);
  fold_kernel<<<1, 256, 0, stream>>>(partials, v1, v2, loop1, loop2);
  convwt_kernel<<<(CONVN + DINv * HCv + HCv * HCv + 255) / 256, 256, 0, stream>>>(
      x, W1, W2, xb, Bt1, Bt2);

  // ---- layer 1
  gemm_mfma_kernel<<<dim3(HCv / 128, (NNODE + 127) / 128), 256, 0, stream>>>(
      xb, Bt1, hb, NNODE, DINv, as1, ad1, al_src, al_dst);
  apre1_kernel<<<(NEDGE + 255) / 256, 256, 0, stream>>>(src_sorted, eid_sorted, ea, al_src,
                                                        v1, v2, ap, ale2s);
  node_kernel<<<(NNODE + 3) / 4, 256, 0, stream>>>(hb, al_src, al_dst, ap, loop1, row_ptr,
                                                   src_sorted, b1, (float*)nullptr, h1b);

  // ---- layer 2
  gemm_mfma_kernel<<<dim3(HCv / 128, (NNODE + 127) / 128), 256, 0, stream>>>(
      h1b, Bt2, hb, NNODE, HCv, as2, ad2, al_src, al_dst);
  apre2_kernel<<<(NEDGE + 255) / 256, 256, 0, stream>>>(src_sorted, ale2s, al_src, ap);
  node_kernel<<<(NNODE + 3) / 4, 256, 0, stream>>>(hb, al_src, al_dst, ap, loop2, row_ptr,
                                                   src_sorted, b2, out, (ushort*)nullptr);
}

// Round 7
// 709.922 us; speedup vs baseline: 1.0859x; 1.0153x over previous
//
#include <hip/hip_runtime.h>
#include <math.h>

#define NNODE 50000
#define NEDGE 800000
#define DINv  128
#define EDv   16
#define NHv   4
#define CHv   128
#define HCv   512
#define SLOPEv 0.2f
#define MEANBLK 512
#define CONVN (NNODE * DINv / 4)

typedef __attribute__((ext_vector_type(8))) short bf16x8;
typedef __attribute__((ext_vector_type(4))) float f32x4;
typedef __attribute__((ext_vector_type(4))) unsigned u32x4;
typedef __attribute__((address_space(3))) unsigned lds_u32;
typedef const __attribute__((address_space(1))) unsigned glb_u32;

__device__ __forceinline__ ushort f2b(float f) {
  unsigned u = __float_as_uint(f);
  u += 0x7FFF + ((u >> 16) & 1);
  return (ushort)(u >> 16);
}
__device__ __forceinline__ float blo(unsigned u) { return __uint_as_float(u << 16); }
__device__ __forceinline__ float bhi(unsigned u) { return __uint_as_float(u & 0xffff0000u); }

__device__ __forceinline__ void nt_store16(void* p, unsigned a, unsigned b, unsigned c,
                                           unsigned d) {
  u32x4 t = {a, b, c, d};
  __builtin_nontemporal_store(t, (u32x4*)p);
}

// ---------------------------------------------------------------- CSR build
__global__ void detect_kernel(const int* __restrict__ ei, int* __restrict__ flag) {
  __shared__ int bad;
  if (threadIdx.x == 0) bad = 0;
  __syncthreads();
  for (int i = threadIdx.x; i < 2048; i += 256)
    if (ei[2 * i + 1] != 0) bad = 1;
  __syncthreads();
  if (threadIdx.x == 0) flag[0] = bad ? 0 : 1;
}

__device__ __forceinline__ int load_idx(const int* __restrict__ ei, int e, int row, int wide) {
  if (wide) return ei[2 * ((size_t)row * NEDGE + e)];
  return ei[(size_t)row * NEDGE + e];
}

__global__ void count_kernel(const int* __restrict__ ei, const int* __restrict__ flag,
                             int* __restrict__ deg) {
  int e = blockIdx.x * blockDim.x + threadIdx.x;
  if (e < NEDGE) {
    int w = flag[0];
    atomicAdd(&deg[load_idx(ei, e, 1, w)], 1);
  }
}

// Writes ONLY the permutation (1 random 4B store/edge; src lookup moved to apre1).
__global__ void scatter_kernel(const int* __restrict__ ei, const int* __restrict__ flag,
                               const int* __restrict__ row_ptr, int* __restrict__ cursor,
                               int* __restrict__ eid_sorted) {
  int e = blockIdx.x * blockDim.x + threadIdx.x;
  if (e < NEDGE) {
    int w = flag[0];
    int d = load_idx(ei, e, 1, w);
    int p = row_ptr[d] + atomicAdd(&cursor[d], 1);
    eid_sorted[p] = e;
  }
}

// ---------------------------------------------------------------- fused mean_part + prep + convwt
__global__ void prep_misc_kernel(const float* __restrict__ ea, float* __restrict__ partials,
                                 const float* __restrict__ We1, const float* __restrict__ ae1,
                                 const float* __restrict__ We2, const float* __restrict__ ae2,
                                 float* __restrict__ v1, float* __restrict__ v2,
                                 const float* __restrict__ x, const float* __restrict__ W1,
                                 const float* __restrict__ W2, ushort* __restrict__ xb,
                                 ushort* __restrict__ Bt1, ushort* __restrict__ Bt2) {
  int b = blockIdx.x;
  if (b < MEANBLK) {
    // ---- mean partials over edge_features
    float acc[EDv];
#pragma unroll
    for (int d = 0; d < EDv; d++) acc[d] = 0.f;
    const int stride = MEANBLK * 256;
    for (int r = b * 256 + threadIdx.x; r < NEDGE; r += stride) {
      const float4* p = (const float4*)(ea + (size_t)r * EDv);
#pragma unroll
      for (int q = 0; q < 4; q++) {
        float4 v = p[q];
        acc[q * 4 + 0] += v.x; acc[q * 4 + 1] += v.y;
        acc[q * 4 + 2] += v.z; acc[q * 4 + 3] += v.w;
      }
    }
    __shared__ float red[4][EDv];
    int wid = threadIdx.x >> 6, lane = threadIdx.x & 63;
#pragma unroll
    for (int d = 0; d < EDv; d++) {
      float v = acc[d];
      for (int off = 32; off; off >>= 1) v += __shfl_down(v, off, 64);
      if (lane == 0) red[wid][d] = v;
    }
    __syncthreads();
    if (threadIdx.x < EDv) {
      float v = red[0][threadIdx.x] + red[1][threadIdx.x] + red[2][threadIdx.x] +
                red[3][threadIdx.x];
      partials[b * EDv + threadIdx.x] = v;
    }
  } else if (b == MEANBLK) {
    // ---- v1,v2 = fold(We, a_e)
    int t = threadIdx.x;
    if (t < 128) {
      int layer = t >> 6, u = t & 63;
      int d = u >> 2, h = u & 3;
      const float* We = layer ? We2 : We1;
      const float* ae = layer ? ae2 : ae1;
      float s = 0.f;
      for (int c = 0; c < CHv; c++) s += We[(size_t)d * HCv + h * CHv + c] * ae[h * CHv + c];
      (layer ? v2 : v1)[d * 4 + h] = s;
    }
  } else {
    // ---- conv x->bf16 + weight transposes
    int i = (b - MEANBLK - 1) * 256 + threadIdx.x;
    if (i < CONVN) {
      float4 v = ((const float4*)x)[i];
      ushort4 o;
      o.x = f2b(v.x); o.y = f2b(v.y); o.z = f2b(v.z); o.w = f2b(v.w);
      ((ushort4*)xb)[i] = o;
    } else if (i < CONVN + DINv * HCv) {
      int idx = i - CONVN;
      int k = idx >> 9, n = idx & (HCv - 1);
      Bt1[(size_t)n * DINv + k] = f2b(W1[idx]);
    } else if (i < CONVN + DINv * HCv + HCv * HCv) {
      int idx = i - CONVN - DINv * HCv;
      int k = idx >> 9, n = idx & (HCv - 1);
      Bt2[(size_t)n * HCv + k] = f2b(W2[idx]);
    }
  }
}

// ---------------------------------------------------------------- fused scan (block 0) + fold (block 1)
__global__ __launch_bounds__(1024) void scan_fold_kernel(
    const int* __restrict__ deg, int* __restrict__ row_ptr,
    const float* __restrict__ partials, const float* __restrict__ v1,
    const float* __restrict__ v2, float* __restrict__ loop1, float* __restrict__ loop2) {
  int tid = threadIdx.x;
  if (blockIdx.x == 0) {
    // ---- exclusive scan of deg, 4 elems/thread
    __shared__ int wsum[16];
    int wid = tid >> 6, lane = tid & 63;
    int carry = 0;
    for (int base = 0; base < NNODE; base += 4096) {
      int idx = base + tid * 4;
      int4 x = make_int4(0, 0, 0, 0);
      if (idx < NNODE) x = *(const int4*)(deg + idx);   // NNODE % 4 == 0
      int t0 = x.x, t1 = t0 + x.y, t2 = t1 + x.z, t3 = t2 + x.w;
      int v = t3;
#pragma unroll
      for (int off = 1; off < 64; off <<= 1) {
        int t = __shfl_up(v, off, 64);
        if (lane >= off) v += t;
      }
      if (lane == 63) wsum[wid] = v;
      __syncthreads();
      if (wid == 0) {
        int s = (lane < 16) ? wsum[lane] : 0;
#pragma unroll
        for (int off = 1; off < 16; off <<= 1) {
          int t = __shfl_up(s, off, 64);
          if (lane >= off) s += t;
        }
        if (lane < 16) wsum[lane] = s;
      }
      __syncthreads();
      int woff = wid ? wsum[wid - 1] : 0;
      int excl = carry + woff + v - t3;
      if (idx < NNODE) {
        int4 o = make_int4(excl, excl + t0, excl + t1, excl + t2);
        *(int4*)(row_ptr + idx) = o;
      }
      carry += wsum[15];
      __syncthreads();
    }
    if (tid == 0) row_ptr[NNODE] = carry;
  } else {
    // ---- fold mean + loop_al_e (1024-thread version)
    __shared__ float buf[1024];
    __shared__ float ms[16];
    int d = tid & 15, r0 = tid >> 4;   // r0 in 0..63
    float v = 0.f;
    for (int r = r0; r < MEANBLK; r += 64) v += partials[r * EDv + d];
    buf[tid] = v;
    __syncthreads();
#pragma unroll
    for (int off = 32; off >= 1; off >>= 1) {
      if (r0 < off) buf[tid] += buf[tid + off * 16];
      __syncthreads();
    }
    if (tid < 16) ms[tid] = buf[tid] * (1.0f / NEDGE);
    __syncthreads();
    if (tid < 8) {
      const float* vv = (tid >> 2) ? v2 : v1;
      int h = tid & 3;
      float a = 0.f;
      for (int d2 = 0; d2 < EDv; d2++) a += ms[d2] * vv[d2 * 4 + h];
      ((tid >> 2) ? loop2 : loop1)[h] = a;
    }
  }
}

// ---------------------------------------------------------------- ap1 = al_src1[s] + ea[e]@v1 ; ale2s = ea[e]@v2
// Also resolves s = ei[e] (random 4B gather) and writes src_sorted sequentially.
__global__ void apre1_kernel(const int* __restrict__ eid_sorted, const int* __restrict__ ei,
                             const int* __restrict__ flag,
                             const float* __restrict__ ea, const float* __restrict__ al_src,
                             const float* __restrict__ v1, const float* __restrict__ v2,
                             float* __restrict__ ap1, float* __restrict__ ale2s,
                             int* __restrict__ src_sorted) {
  __shared__ float sv1[64], sv2[64];
  if (threadIdx.x < 64) sv1[threadIdx.x] = v1[threadIdx.x];
  else if (threadIdx.x < 128) sv2[threadIdx.x - 64] = v2[threadIdx.x - 64];
  __syncthreads();
  int p = blockIdx.x * 256 + threadIdx.x;
  if (p >= NEDGE) return;
  int e = eid_sorted[p];
  int w = flag[0];
  int s = load_idx(ei, e, 0, w);
  const float4* pr = (const float4*)(ea + (size_t)e * EDv);
  float row[16];
  *(float4*)&row[0] = pr[0]; *(float4*)&row[4] = pr[1];
  *(float4*)&row[8] = pr[2]; *(float4*)&row[12] = pr[3];
  float a0 = 0, a1 = 0, a2 = 0, a3 = 0;
  float b0 = 0, b1 = 0, b2 = 0, b3 = 0;
#pragma unroll
  for (int d = 0; d < 16; d++) {
    a0 += row[d] * sv1[d * 4 + 0];
    a1 += row[d] * sv1[d * 4 + 1];
    a2 += row[d] * sv1[d * 4 + 2];
    a3 += row[d] * sv1[d * 4 + 3];
    b0 += row[d] * sv2[d * 4 + 0];
    b1 += row[d] * sv2[d * 4 + 1];
    b2 += row[d] * sv2[d * 4 + 2];
    b3 += row[d] * sv2[d * 4 + 3];
  }
  float4 as = ((const float4*)al_src)[s];
  ((float4*)ap1)[p] = make_float4(as.x + a0, as.y + a1, as.z + a2, as.w + a3);
  ((float4*)ale2s)[p] = make_float4(b0, b1, b2, b3);
  src_sorted[p] = s;
}

// ---------------------------------------------------------------- ap2 = al_src2[s] + ale2s (seq)
__global__ void apre2_kernel(const int* __restrict__ src_sorted, const float* __restrict__ ale2s,
                             const float* __restrict__ al_src, float* __restrict__ ap2) {
  int p = blockIdx.x * 256 + threadIdx.x;
  if (p >= NEDGE) return;
  int s = src_sorted[p];
  float4 a = ((const float4*)al_src)[s];
  float4 b = ((const float4*)ale2s)[p];
  ((float4*)ap2)[p] = make_float4(a.x + b.x, a.y + b.y, a.z + b.z, a.w + b.w);
}

// ---------------------------------------------------------------- bf16 MFMA GEMM (BK=64) + fused rowdots
__global__ __launch_bounds__(256) void gemm_mfma_kernel(const ushort* __restrict__ A,
                                                        const ushort* __restrict__ Bt,
                                                        ushort* __restrict__ C, int M, int K,
                                                        const float* __restrict__ a_src,
                                                        const float* __restrict__ a_dst,
                                                        float* __restrict__ al_src,
                                                        float* __restrict__ al_dst) {
  __shared__ ushort As[8][128][8];  // 16 KB
  __shared__ ushort Bs[8][128][8];  // 16 KB
  __shared__ float ssa[128], ssd[128];
  __shared__ float rsum[2][128][2];
  int tid = threadIdx.x;
  int wid = tid >> 6, lane = tid & 63;

  // bijective XCD-chunk swizzle over gridDim.x * gridDim.y blocks (x fastest)
  int nblk = gridDim.x * gridDim.y;
  int j = blockIdx.y * gridDim.x + blockIdx.x;
  int q = nblk >> 3, rem = nblk & 7;
  int xcd = j & 7, idx = j >> 3;
  int d = (xcd < rem) ? xcd * (q + 1) + idx : rem * (q + 1) + (xcd - rem) * q + idx;
  int rb = (d >> 2) * 128, cb = (d & 3) * 128;
  int hblk = cb >> 7;

  int wm = (wid >> 1) * 64, wn = (wid & 1) * 64;
  int lr = lane & 15, lq = lane >> 4;

  if (tid < 128) { ssa[tid] = a_src[cb + tid]; ssd[tid] = a_dst[cb + tid]; }

  f32x4 acc[4][4];
#pragma unroll
  for (int i = 0; i < 4; i++)
#pragma unroll
    for (int jx = 0; jx < 4; jx++) acc[i][jx] = (f32x4){0.f, 0.f, 0.f, 0.f};

  ushort* AsF = &As[0][0][0];
  ushort* BsF = &Bs[0][0][0];

  for (int k0 = 0; k0 < K; k0 += 64) {
#pragma unroll
    for (int s = 0; s < 4; s++) {
      int c = s * 256 + tid;        // chunk = kq*128 + m, kq in 0..7
      int kq = c >> 7, m = c & 127;
      int row = rb + m; if (row >= M) row = M - 1;
      const ushort* gA = A + (size_t)row * K + k0 + kq * 8;
      __builtin_amdgcn_global_load_lds((glb_u32*)gA, (lds_u32*)(AsF + (size_t)c * 8), 16, 0, 0);
    }
#pragma unroll
    for (int s = 0; s < 4; s++) {
      int c = s * 256 + tid;        // chunk = kq*128 + n
      int kq = c >> 7, n = c & 127;
      const ushort* gB = Bt + (size_t)(cb + n) * K + k0 + kq * 8;
      __builtin_amdgcn_global_load_lds((glb_u32*)gB, (lds_u32*)(BsF + (size_t)c * 8), 16, 0, 0);
    }
    __syncthreads();
#pragma unroll
    for (int hh = 0; hh < 2; hh++) {
      bf16x8 af[4], bfr[4];
#pragma unroll
      for (int i = 0; i < 4; i++) {
        af[i]  = *(const bf16x8*)&As[hh * 4 + lq][wm + i * 16 + lr][0];
        bfr[i] = *(const bf16x8*)&Bs[hh * 4 + lq][wn + i * 16 + lr][0];
      }
#pragma unroll
      for (int i = 0; i < 4; i++)
#pragma unroll
        for (int jx = 0; jx < 4; jx++)
          acc[i][jx] = __builtin_amdgcn_mfma_f32_16x16x32_bf16(af[i], bfr[jx], acc[i][jx], 0, 0, 0);
    }
    __syncthreads();
  }

  // C store (bf16)
#pragma unroll
  for (int i = 0; i < 4; i++) {
    int rbase = rb + wm + i * 16 + lq * 4;
#pragma unroll
    for (int jx = 0; jx < 4; jx++) {
      int col = cb + wn + jx * 16 + lr;
#pragma unroll
      for (int r = 0; r < 4; r++) {
        int row = rbase + r;
        if (row < M) C[(size_t)row * HCv + col] = f2b(acc[i][jx][r]);
      }
    }
  }

  // fused rowdots epilogue
  float sa[4], sd[4];
#pragma unroll
  for (int jx = 0; jx < 4; jx++) {
    int c = wn + jx * 16 + lr;
    sa[jx] = ssa[c]; sd[jx] = ssd[c];
  }
#pragma unroll
  for (int i = 0; i < 4; i++) {
#pragma unroll
    for (int r = 0; r < 4; r++) {
      float s1 = 0.f, s2 = 0.f;
#pragma unroll
      for (int jx = 0; jx < 4; jx++) {
        s1 = fmaf(acc[i][jx][r], sa[jx], s1);
        s2 = fmaf(acc[i][jx][r], sd[jx], s2);
      }
#pragma unroll
      for (int off = 1; off < 16; off <<= 1) {
        s1 += __shfl_xor(s1, off, 16);
        s2 += __shfl_xor(s2, off, 16);
      }
      if (lr == 0) {
        int row = wm + i * 16 + lq * 4 + r;
        rsum[0][row][wn >> 6] = s1;
        rsum[1][row][wn >> 6] = s2;
      }
    }
  }
  __syncthreads();
  if (tid < 128) {
    int row = rb + tid;
    if (row < M) {
      al_src[(size_t)row * 4 + hblk] = rsum[0][tid][0] + rsum[0][tid][1];
      al_dst[(size_t)row * 4 + hblk] = rsum[1][tid][0] + rsum[1][tid][1];
    }
  }
}

// ---------------------------------------------------------------- per-node softmax + aggregate
// ONE WAVE PER NODE, no max pass; sequential ap reads; gather batched 4-deep; NT output.
__device__ __forceinline__ void fma8(float* acc, float w, uint4 u) {
  acc[0] = fmaf(w, blo(u.x), acc[0]);
  acc[1] = fmaf(w, bhi(u.x), acc[1]);
  acc[2] = fmaf(w, blo(u.y), acc[2]);
  acc[3] = fmaf(w, bhi(u.y), acc[3]);
  acc[4] = fmaf(w, blo(u.z), acc[4]);
  acc[5] = fmaf(w, bhi(u.z), acc[5]);
  acc[6] = fmaf(w, blo(u.w), acc[6]);
  acc[7] = fmaf(w, bhi(u.w), acc[7]);
}

__global__ __launch_bounds__(256) void node_kernel(
    const ushort* __restrict__ hb, const float* __restrict__ al_src,
    const float* __restrict__ al_dst, const float* __restrict__ ap,
    const float* __restrict__ loop_al_e, const int* __restrict__ row_ptr,
    const int* __restrict__ src_sorted, const float* __restrict__ bias,
    float* __restrict__ outf, ushort* __restrict__ outb) {
  int wid = threadIdx.x >> 6, lane = threadIdx.x & 63;
  int n = blockIdx.x * 4 + wid;
  if (n >= NNODE) return;
  int base = row_ptr[n];
  int deg = row_ptr[n + 1] - base;
  int h = lane >> 4;     // head of this lane's 8 columns
  int jj = lane & 15;    // edge slot within a 16-edge chunk

  float aldh = al_dst[(size_t)n * 4 + h];
  float a0 = al_src[(size_t)n * 4 + h] + aldh + loop_al_e[h];
  float alph = a0 > 0.f ? a0 : SLOPEv * a0;
  float wl = __expf(alph);

  // self row, issued early
  uint4 uself = *((const uint4*)(hb + ((size_t)n << 9)) + lane);

  float acc[8];
#pragma unroll
  for (int q = 0; q < 8; q++) acc[q] = 0.f;
  float den = 0.f;

  for (int cs = 0; cs < deg; cs += 16) {
    int cl = min(16, deg - cs);
    float w = 0.f;
    int sv = 0;
    if (jj < cl) {
      int p = base + cs + jj;
      sv = src_sorted[p];
      float a = ap[(size_t)p * 4 + h] + aldh;
      a = a > 0.f ? a : SLOPEv * a;
      w = __expf(a);
      den += w;
    }
    int cl4 = (cl + 3) & ~3;   // lanes j>=cl have w=0, sv=0 (harmless hot row-0 load)
    for (int j0 = 0; j0 < cl4; j0 += 4) {
      int s0 = __shfl(sv, j0 + 0, 16);
      int s1 = __shfl(sv, j0 + 1, 16);
      int s2 = __shfl(sv, j0 + 2, 16);
      int s3 = __shfl(sv, j0 + 3, 16);
      float w0 = __shfl(w, j0 + 0, 16);
      float w1 = __shfl(w, j0 + 1, 16);
      float w2 = __shfl(w, j0 + 2, 16);
      float w3 = __shfl(w, j0 + 3, 16);
      uint4 u0 = *((const uint4*)(hb + ((size_t)s0 << 9)) + lane);
      uint4 u1 = *((const uint4*)(hb + ((size_t)s1 << 9)) + lane);
      uint4 u2 = *((const uint4*)(hb + ((size_t)s2 << 9)) + lane);
      uint4 u3 = *((const uint4*)(hb + ((size_t)s3 << 9)) + lane);
      fma8(acc, w0, u0);
      fma8(acc, w1, u1);
      fma8(acc, w2, u2);
      fma8(acc, w3, u3);
    }
  }

  // self loop
  fma8(acc, wl, uself);

  // denominator: reduce over the 16 j-slots within each head group
#pragma unroll
  for (int off = 8; off; off >>= 1) den += __shfl_xor(den, off, 16);
  den += wl;
  float rden = 1.f / (den + 1e-16f);

  // epilogue
  const float4* bp = (const float4*)(bias + lane * 8);
  float4 b0 = bp[0], b1 = bp[1];
  float bv[8] = {b0.x, b0.y, b0.z, b0.w, b1.x, b1.y, b1.z, b1.w};
  float r[8];
#pragma unroll
  for (int q = 0; q < 8; q++) {
    float t = acc[q] * rden + bv[q];
    r[q] = t > 0.f ? t : expm1f(t);
  }
  if (outf) {
    float* op = outf + (size_t)n * HCv + lane * 8;
    nt_store16(op, __float_as_uint(r[0]), __float_as_uint(r[1]),
               __float_as_uint(r[2]), __float_as_uint(r[3]));
    nt_store16(op + 4, __float_as_uint(r[4]), __float_as_uint(r[5]),
               __float_as_uint(r[6]), __float_as_uint(r[7]));
  }
  if (outb) {
    nt_store16(outb + (size_t)n * HCv + lane * 8,
               (unsigned)f2b(r[0]) | ((unsigned)f2b(r[1]) << 16),
               (unsigned)f2b(r[2]) | ((unsigned)f2b(r[3]) << 16),
               (unsigned)f2b(r[4]) | ((unsigned)f2b(r[5]) << 16),
               (unsigned)f2b(r[6]) | ((unsigned)f2b(r[7]) << 16));
  }
}

// ---------------------------------------------------------------- launch
static inline char* take(char*& p, size_t bytes) {
  char* r = p;
  p += (bytes + 255) & ~(size_t)255;
  return r;
}

extern "C" void kernel_launch(void* const* d_in, const int* in_sizes, int n_in,
                              void* d_out, int out_size, void* d_ws, size_t ws_size,
                              hipStream_t stream) {
  (void)in_sizes; (void)n_in; (void)out_size; (void)ws_size;
  const float* x   = (const float*)d_in[0];
  const int*   ei  = (const int*)d_in[1];
  const float* ea  = (const float*)d_in[2];
  const float* W1  = (const float*)d_in[3];
  const float* as1 = (const float*)d_in[4];
  const float* ad1 = (const float*)d_in[5];
  const float* We1 = (const float*)d_in[6];
  const float* ae1 = (const float*)d_in[7];
  const float* b1  = (const float*)d_in[8];
  const float* W2  = (const float*)d_in[9];
  const float* as2 = (const float*)d_in[10];
  const float* ad2 = (const float*)d_in[11];
  const float* We2 = (const float*)d_in[12];
  const float* ae2 = (const float*)d_in[13];
  const float* b2  = (const float*)d_in[14];
  float* out = (float*)d_out;

  char* p = (char*)d_ws;
  ushort* hb        = (ushort*)take(p, (size_t)NNODE * HCv * 2);
  float* al_src     = (float*)take(p, (size_t)NNODE * 4 * 4);
  float* al_dst     = (float*)take(p, (size_t)NNODE * 4 * 4);
  float* ap         = (float*)take(p, (size_t)NEDGE * 4 * 4);
  float* ale2s      = (float*)take(p, (size_t)NEDGE * 4 * 4);
  int*   src_sorted = (int*)take(p, (size_t)NEDGE * 4);
  int*   eid_sorted = (int*)take(p, (size_t)NEDGE * 4);
  int*   row_ptr    = (int*)take(p, (size_t)(NNODE + 1) * 4);
  float* partials   = (float*)take(p, (size_t)MEANBLK * EDv * 4);
  ushort* Bt1       = (ushort*)take(p, (size_t)HCv * DINv * 2);
  ushort* Bt2       = (ushort*)take(p, (size_t)HCv * HCv * 2);
  char* zero_begin = p;
  int*   deg        = (int*)take(p, (size_t)NNODE * 4);
  int*   cursor     = (int*)take(p, (size_t)NNODE * 4);
  size_t zero_len = (size_t)(p - zero_begin);
  float* v1         = (float*)take(p, 64 * 4);
  float* v2         = (float*)take(p, 64 * 4);
  float* loop1      = (float*)take(p, 4 * 4);
  float* loop2      = (float*)take(p, 4 * 4);
  int*   flag       = (int*)take(p, 4);

  // scratch carved out of d_out (102.4 MB): xb dead after layer-1 gemm,
  // h1b dead after layer-2 gemm; final out written only by the last node_kernel.
  ushort* xb  = (ushort*)d_out;                                       // 12.8 MB
  ushort* h1b = (ushort*)((char*)d_out + (size_t)16 * 1024 * 1024);   // 51.2 MB

  hipMemsetAsync(zero_begin, 0, zero_len, stream);

  detect_kernel<<<1, 256, 0, stream>>>(ei, flag);
  count_kernel<<<(NEDGE + 255) / 256, 256, 0, stream>>>(ei, flag, deg);
  prep_misc_kernel<<<MEANBLK + 1 + (CONVN + DINv * HCv + HCv * HCv + 255) / 256, 256, 0,
                     stream>>>(ea, partials, We1, ae1, We2, ae2, v1, v2, x, W1, W2, xb, Bt1, Bt2);
  scan_fold_kernel<<<2, 1024, 0, stream>>>(deg, row_ptr, partials, v1, v2, loop1, loop2);
  scatter_kernel<<<(NEDGE + 255) / 256, 256, 0, stream>>>(ei, flag, row_ptr, cursor, eid_sorted);

  // ---- layer 1
  gemm_mfma_kernel<<<dim3(HCv / 128, (NNODE + 127) / 128), 256, 0, stream>>>(
      xb, Bt1, hb, NNODE, DINv, as1, ad1, al_src, al_dst);
  apre1_kernel<<<(NEDGE + 255) / 256, 256, 0, stream>>>(eid_sorted, ei, flag, ea, al_src,
                                                        v1, v2, ap, ale2s, src_sorted);
  node_kernel<<<(NNODE + 3) / 4, 256, 0, stream>>>(hb, al_src, al_dst, ap, loop1, row_ptr,
                                                   src_sorted, b1, (float*)nullptr, h1b);

  // ---- layer 2
  gemm_mfma_kernel<<<dim3(HCv / 128, (NNODE + 127) / 128), 256, 0, stream>>>(
      h1b, Bt2, hb, NNODE, HCv, as2, ad2, al_src, al_dst);
  apre2_kernel<<<(NEDGE + 255) / 256, 256, 0, stream>>>(src_sorted, ale2s, al_src, ap);
  node_kernel<<<(NNODE + 3) / 4, 256, 0, stream>>>(hb, al_src, al_dst, ap, loop2, row_ptr,
                                                   src_sorted, b2, out, (ushort*)nullptr);
}

// Round 8
// 679.563 us; speedup vs baseline: 1.1344x; 1.0447x over previous
//
#include <hip/hip_runtime.h>
#include <math.h>

#define NNODE 50000
#define NEDGE 800000
#define DINv  128
#define EDv   16
#define NHv   4
#define CHv   128
#define HCv   512
#define SLOPEv 0.2f
#define MEANBLK 512
#define CONVN (NNODE * DINv / 4)
#define NCOUNT ((NEDGE + 255) / 256)

typedef __attribute__((ext_vector_type(8))) short bf16x8;
typedef __attribute__((ext_vector_type(4))) float f32x4;
typedef __attribute__((ext_vector_type(4))) unsigned u32x4;
typedef __attribute__((address_space(3))) unsigned lds_u32;
typedef const __attribute__((address_space(1))) unsigned glb_u32;

__device__ __forceinline__ ushort f2b(float f) {
  unsigned u = __float_as_uint(f);
  u += 0x7FFF + ((u >> 16) & 1);
  return (ushort)(u >> 16);
}
__device__ __forceinline__ float blo(unsigned u) { return __uint_as_float(u << 16); }
__device__ __forceinline__ float bhi(unsigned u) { return __uint_as_float(u & 0xffff0000u); }

__device__ __forceinline__ void nt_store16(void* p, unsigned a, unsigned b, unsigned c,
                                           unsigned d) {
  u32x4 t = {a, b, c, d};
  __builtin_nontemporal_store(t, (u32x4*)p);
}

// ---------------------------------------------------------------- detect int64 vs int32 layout
__global__ void detect_kernel(const int* __restrict__ ei, int* __restrict__ flag) {
  __shared__ int bad;
  if (threadIdx.x == 0) bad = 0;
  __syncthreads();
  for (int i = threadIdx.x; i < 2048; i += 256)
    if (ei[2 * i + 1] != 0) bad = 1;
  __syncthreads();
  if (threadIdx.x == 0) flag[0] = bad ? 0 : 1;
}

__device__ __forceinline__ int load_idx(const int* __restrict__ ei, int e, int row, int wide) {
  if (wide) return ei[2 * ((size_t)row * NEDGE + e)];
  return ei[(size_t)row * NEDGE + e];
}

// ---------------------------------------------------------------- fused count + mean_part + prep + convwt
__global__ void prep_misc_kernel(const int* __restrict__ ei, const int* __restrict__ flag,
                                 int* __restrict__ deg,
                                 const float* __restrict__ ea, float* __restrict__ partials,
                                 const float* __restrict__ We1, const float* __restrict__ ae1,
                                 const float* __restrict__ We2, const float* __restrict__ ae2,
                                 float* __restrict__ v1, float* __restrict__ v2,
                                 const float* __restrict__ x, const float* __restrict__ W1,
                                 const float* __restrict__ W2, ushort* __restrict__ xb,
                                 ushort* __restrict__ Bt1, ushort* __restrict__ Bt2) {
  int b = blockIdx.x;
  if (b < NCOUNT) {
    // ---- degree count (random atomics, latency-bound — overlaps the BW work below)
    int e = b * 256 + threadIdx.x;
    if (e < NEDGE) {
      int w = flag[0];
      atomicAdd(&deg[load_idx(ei, e, 1, w)], 1);
    }
    return;
  }
  b -= NCOUNT;
  if (b < MEANBLK) {
    // ---- mean partials over edge_features
    float acc[EDv];
#pragma unroll
    for (int d = 0; d < EDv; d++) acc[d] = 0.f;
    const int stride = MEANBLK * 256;
    for (int r = b * 256 + threadIdx.x; r < NEDGE; r += stride) {
      const float4* p = (const float4*)(ea + (size_t)r * EDv);
#pragma unroll
      for (int q = 0; q < 4; q++) {
        float4 v = p[q];
        acc[q * 4 + 0] += v.x; acc[q * 4 + 1] += v.y;
        acc[q * 4 + 2] += v.z; acc[q * 4 + 3] += v.w;
      }
    }
    __shared__ float red[4][EDv];
    int wid = threadIdx.x >> 6, lane = threadIdx.x & 63;
#pragma unroll
    for (int d = 0; d < EDv; d++) {
      float v = acc[d];
      for (int off = 32; off; off >>= 1) v += __shfl_down(v, off, 64);
      if (lane == 0) red[wid][d] = v;
    }
    __syncthreads();
    if (threadIdx.x < EDv) {
      float v = red[0][threadIdx.x] + red[1][threadIdx.x] + red[2][threadIdx.x] +
                red[3][threadIdx.x];
      partials[b * EDv + threadIdx.x] = v;
    }
  } else if (b == MEANBLK) {
    // ---- v1,v2 = fold(We, a_e)
    int t = threadIdx.x;
    if (t < 128) {
      int layer = t >> 6, u = t & 63;
      int d = u >> 2, h = u & 3;
      const float* We = layer ? We2 : We1;
      const float* ae = layer ? ae2 : ae1;
      float s = 0.f;
      for (int c = 0; c < CHv; c++) s += We[(size_t)d * HCv + h * CHv + c] * ae[h * CHv + c];
      (layer ? v2 : v1)[d * 4 + h] = s;
    }
  } else {
    // ---- conv x->bf16 + weight transposes
    int i = (b - MEANBLK - 1) * 256 + threadIdx.x;
    if (i < CONVN) {
      float4 v = ((const float4*)x)[i];
      ushort4 o;
      o.x = f2b(v.x); o.y = f2b(v.y); o.z = f2b(v.z); o.w = f2b(v.w);
      ((ushort4*)xb)[i] = o;
    } else if (i < CONVN + DINv * HCv) {
      int idx = i - CONVN;
      int k = idx >> 9, n = idx & (HCv - 1);
      Bt1[(size_t)n * DINv + k] = f2b(W1[idx]);
    } else if (i < CONVN + DINv * HCv + HCv * HCv) {
      int idx = i - CONVN - DINv * HCv;
      int k = idx >> 9, n = idx & (HCv - 1);
      Bt2[(size_t)n * HCv + k] = f2b(W2[idx]);
    }
  }
}

// ---------------------------------------------------------------- fused scan (block 0) + fold (block 1)
__global__ __launch_bounds__(1024) void scan_fold_kernel(
    const int* __restrict__ deg, int* __restrict__ row_ptr,
    const float* __restrict__ partials, const float* __restrict__ v1,
    const float* __restrict__ v2, float* __restrict__ loop1, float* __restrict__ loop2) {
  int tid = threadIdx.x;
  if (blockIdx.x == 0) {
    __shared__ int wsum[16];
    int wid = tid >> 6, lane = tid & 63;
    int carry = 0;
    for (int base = 0; base < NNODE; base += 4096) {
      int idx = base + tid * 4;
      int4 x = make_int4(0, 0, 0, 0);
      if (idx < NNODE) x = *(const int4*)(deg + idx);   // NNODE % 4 == 0
      int t0 = x.x, t1 = t0 + x.y, t2 = t1 + x.z, t3 = t2 + x.w;
      int v = t3;
#pragma unroll
      for (int off = 1; off < 64; off <<= 1) {
        int t = __shfl_up(v, off, 64);
        if (lane >= off) v += t;
      }
      if (lane == 63) wsum[wid] = v;
      __syncthreads();
      if (wid == 0) {
        int s = (lane < 16) ? wsum[lane] : 0;
#pragma unroll
        for (int off = 1; off < 16; off <<= 1) {
          int t = __shfl_up(s, off, 64);
          if (lane >= off) s += t;
        }
        if (lane < 16) wsum[lane] = s;
      }
      __syncthreads();
      int woff = wid ? wsum[wid - 1] : 0;
      int excl = carry + woff + v - t3;
      if (idx < NNODE) {
        int4 o = make_int4(excl, excl + t0, excl + t1, excl + t2);
        *(int4*)(row_ptr + idx) = o;
      }
      carry += wsum[15];
      __syncthreads();
    }
    if (tid == 0) row_ptr[NNODE] = carry;
  } else {
    __shared__ float buf[1024];
    __shared__ float ms[16];
    int d = tid & 15, r0 = tid >> 4;   // r0 in 0..63
    float v = 0.f;
    for (int r = r0; r < MEANBLK; r += 64) v += partials[r * EDv + d];
    buf[tid] = v;
    __syncthreads();
#pragma unroll
    for (int off = 32; off >= 1; off >>= 1) {
      if (r0 < off) buf[tid] += buf[tid + off * 16];
      __syncthreads();
    }
    if (tid < 16) ms[tid] = buf[tid] * (1.0f / NEDGE);
    __syncthreads();
    if (tid < 8) {
      const float* vv = (tid >> 2) ? v2 : v1;
      int h = tid & 3;
      float a = 0.f;
      for (int d2 = 0; d2 < EDv; d2++) a += ms[d2] * vv[d2 * 4 + h];
      ((tid >> 2) ? loop2 : loop1)[h] = a;
    }
  }
}

// ---------------------------------------------------------------- ap1 = al_src1[s] + ea[e]@v1 ; ale2s = ea[e]@v2
__global__ void apre1_kernel(const int* __restrict__ eid_sorted, const int* __restrict__ ei,
                             const int* __restrict__ flag,
                             const float* __restrict__ ea, const float* __restrict__ al_src,
                             const float* __restrict__ v1, const float* __restrict__ v2,
                             float* __restrict__ ap1, float* __restrict__ ale2s,
                             int* __restrict__ src_sorted) {
  __shared__ float sv1[64], sv2[64];
  if (threadIdx.x < 64) sv1[threadIdx.x] = v1[threadIdx.x];
  else if (threadIdx.x < 128) sv2[threadIdx.x - 64] = v2[threadIdx.x - 64];
  __syncthreads();
  int p = blockIdx.x * 256 + threadIdx.x;
  if (p >= NEDGE) return;
  int e = eid_sorted[p];
  int w = flag[0];
  int s = load_idx(ei, e, 0, w);
  const float4* pr = (const float4*)(ea + (size_t)e * EDv);
  float row[16];
  *(float4*)&row[0] = pr[0]; *(float4*)&row[4] = pr[1];
  *(float4*)&row[8] = pr[2]; *(float4*)&row[12] = pr[3];
  float a0 = 0, a1 = 0, a2 = 0, a3 = 0;
  float b0 = 0, b1 = 0, b2 = 0, b3 = 0;
#pragma unroll
  for (int d = 0; d < 16; d++) {
    a0 += row[d] * sv1[d * 4 + 0];
    a1 += row[d] * sv1[d * 4 + 1];
    a2 += row[d] * sv1[d * 4 + 2];
    a3 += row[d] * sv1[d * 4 + 3];
    b0 += row[d] * sv2[d * 4 + 0];
    b1 += row[d] * sv2[d * 4 + 1];
    b2 += row[d] * sv2[d * 4 + 2];
    b3 += row[d] * sv2[d * 4 + 3];
  }
  float4 as = ((const float4*)al_src)[s];
  ((float4*)ap1)[p] = make_float4(as.x + a0, as.y + a1, as.z + a2, as.w + a3);
  ((float4*)ale2s)[p] = make_float4(b0, b1, b2, b3);
  src_sorted[p] = s;
}

// ---------------------------------------------------------------- bf16 MFMA GEMM (BK=64) + fused rowdots
//                                                                   + optional scatter tail blocks
__global__ __launch_bounds__(256) void gemm_mfma_kernel(const ushort* __restrict__ A,
                                                        const ushort* __restrict__ Bt,
                                                        ushort* __restrict__ C, int M, int K,
                                                        const float* __restrict__ a_src,
                                                        const float* __restrict__ a_dst,
                                                        float* __restrict__ al_src,
                                                        float* __restrict__ al_dst,
                                                        int ngemm,
                                                        const int* __restrict__ ei,
                                                        const int* __restrict__ flag,
                                                        const int* __restrict__ row_ptr,
                                                        int* __restrict__ cursor,
                                                        int* __restrict__ eid_sorted) {
  int j = blockIdx.x;
  if (j >= ngemm) {
    // ---- scatter tail: build destination-sorted edge permutation
    int e = (j - ngemm) * 256 + threadIdx.x;
    if (e < NEDGE) {
      int w = flag[0];
      int d0 = load_idx(ei, e, 1, w);
      int p = row_ptr[d0] + atomicAdd(&cursor[d0], 1);
      eid_sorted[p] = e;
    }
    return;
  }

  __shared__ ushort As[8][128][8];  // 16 KB
  __shared__ ushort Bs[8][128][8];  // 16 KB
  __shared__ float ssa[128], ssd[128];
  __shared__ float rsum[2][128][2];
  int tid = threadIdx.x;
  int wid = tid >> 6, lane = tid & 63;

  // bijective XCD-chunk swizzle over ngemm blocks
  int q = ngemm >> 3, rem = ngemm & 7;
  int xcd = j & 7, idx = j >> 3;
  int d = (xcd < rem) ? xcd * (q + 1) + idx : rem * (q + 1) + (xcd - rem) * q + idx;
  int rb = (d >> 2) * 128, cb = (d & 3) * 128;
  int hblk = cb >> 7;

  int wm = (wid >> 1) * 64, wn = (wid & 1) * 64;
  int lr = lane & 15, lq = lane >> 4;

  if (tid < 128) { ssa[tid] = a_src[cb + tid]; ssd[tid] = a_dst[cb + tid]; }

  f32x4 acc[4][4];
#pragma unroll
  for (int i = 0; i < 4; i++)
#pragma unroll
    for (int jx = 0; jx < 4; jx++) acc[i][jx] = (f32x4){0.f, 0.f, 0.f, 0.f};

  ushort* AsF = &As[0][0][0];
  ushort* BsF = &Bs[0][0][0];

  for (int k0 = 0; k0 < K; k0 += 64) {
#pragma unroll
    for (int s = 0; s < 4; s++) {
      int c = s * 256 + tid;        // chunk = kq*128 + m, kq in 0..7
      int kq = c >> 7, m = c & 127;
      int row = rb + m; if (row >= M) row = M - 1;
      const ushort* gA = A + (size_t)row * K + k0 + kq * 8;
      __builtin_amdgcn_global_load_lds((glb_u32*)gA, (lds_u32*)(AsF + (size_t)c * 8), 16, 0, 0);
    }
#pragma unroll
    for (int s = 0; s < 4; s++) {
      int c = s * 256 + tid;        // chunk = kq*128 + n
      int kq = c >> 7, n = c & 127;
      const ushort* gB = Bt + (size_t)(cb + n) * K + k0 + kq * 8;
      __builtin_amdgcn_global_load_lds((glb_u32*)gB, (lds_u32*)(BsF + (size_t)c * 8), 16, 0, 0);
    }
    __syncthreads();
#pragma unroll
    for (int hh = 0; hh < 2; hh++) {
      bf16x8 af[4], bfr[4];
#pragma unroll
      for (int i = 0; i < 4; i++) {
        af[i]  = *(const bf16x8*)&As[hh * 4 + lq][wm + i * 16 + lr][0];
        bfr[i] = *(const bf16x8*)&Bs[hh * 4 + lq][wn + i * 16 + lr][0];
      }
#pragma unroll
      for (int i = 0; i < 4; i++)
#pragma unroll
        for (int jx = 0; jx < 4; jx++)
          acc[i][jx] = __builtin_amdgcn_mfma_f32_16x16x32_bf16(af[i], bfr[jx], acc[i][jx], 0, 0, 0);
    }
    __syncthreads();
  }

  // C store (bf16)
#pragma unroll
  for (int i = 0; i < 4; i++) {
    int rbase = rb + wm + i * 16 + lq * 4;
#pragma unroll
    for (int jx = 0; jx < 4; jx++) {
      int col = cb + wn + jx * 16 + lr;
#pragma unroll
      for (int r = 0; r < 4; r++) {
        int row = rbase + r;
        if (row < M) C[(size_t)row * HCv + col] = f2b(acc[i][jx][r]);
      }
    }
  }

  // fused rowdots epilogue
  float sa[4], sd[4];
#pragma unroll
  for (int jx = 0; jx < 4; jx++) {
    int c = wn + jx * 16 + lr;
    sa[jx] = ssa[c]; sd[jx] = ssd[c];
  }
#pragma unroll
  for (int i = 0; i < 4; i++) {
#pragma unroll
    for (int r = 0; r < 4; r++) {
      float s1 = 0.f, s2 = 0.f;
#pragma unroll
      for (int jx = 0; jx < 4; jx++) {
        s1 = fmaf(acc[i][jx][r], sa[jx], s1);
        s2 = fmaf(acc[i][jx][r], sd[jx], s2);
      }
#pragma unroll
      for (int off = 1; off < 16; off <<= 1) {
        s1 += __shfl_xor(s1, off, 16);
        s2 += __shfl_xor(s2, off, 16);
      }
      if (lr == 0) {
        int row = wm + i * 16 + lq * 4 + r;
        rsum[0][row][wn >> 6] = s1;
        rsum[1][row][wn >> 6] = s2;
      }
    }
  }
  __syncthreads();
  if (tid < 128) {
    int row = rb + tid;
    if (row < M) {
      al_src[(size_t)row * 4 + hblk] = rsum[0][tid][0] + rsum[0][tid][1];
      al_dst[(size_t)row * 4 + hblk] = rsum[1][tid][0] + rsum[1][tid][1];
    }
  }
}

// ---------------------------------------------------------------- per-node softmax + aggregate
// ONE WAVE PER NODE. If asrc_g != null, alpha adds al_src[sv] inline (layer 2, kills apre2).
__device__ __forceinline__ void fma8(float* acc, float w, uint4 u) {
  acc[0] = fmaf(w, blo(u.x), acc[0]);
  acc[1] = fmaf(w, bhi(u.x), acc[1]);
  acc[2] = fmaf(w, blo(u.y), acc[2]);
  acc[3] = fmaf(w, bhi(u.y), acc[3]);
  acc[4] = fmaf(w, blo(u.z), acc[4]);
  acc[5] = fmaf(w, bhi(u.z), acc[5]);
  acc[6] = fmaf(w, blo(u.w), acc[6]);
  acc[7] = fmaf(w, bhi(u.w), acc[7]);
}

__global__ __launch_bounds__(256) void node_kernel(
    const ushort* __restrict__ hb, const float* __restrict__ al_src,
    const float* __restrict__ al_dst, const float* __restrict__ ap,
    const float* __restrict__ loop_al_e, const int* __restrict__ row_ptr,
    const int* __restrict__ src_sorted, const float* __restrict__ bias,
    const float* __restrict__ asrc_g,
    float* __restrict__ outf, ushort* __restrict__ outb) {
  int wid = threadIdx.x >> 6, lane = threadIdx.x & 63;
  int n = blockIdx.x * 4 + wid;
  if (n >= NNODE) return;
  int base = row_ptr[n];
  int deg = row_ptr[n + 1] - base;
  int h = lane >> 4;     // head of this lane's 8 columns
  int jj = lane & 15;    // edge slot within a 16-edge chunk

  float aldh = al_dst[(size_t)n * 4 + h];
  float a0 = al_src[(size_t)n * 4 + h] + aldh + loop_al_e[h];
  float alph = a0 > 0.f ? a0 : SLOPEv * a0;
  float wl = __expf(alph);

  // self row, issued early
  uint4 uself = *((const uint4*)(hb + ((size_t)n << 9)) + lane);

  float acc[8];
#pragma unroll
  for (int q = 0; q < 8; q++) acc[q] = 0.f;
  float den = 0.f;

  for (int cs = 0; cs < deg; cs += 16) {
    int cl = min(16, deg - cs);
    float w = 0.f;
    int sv = 0;
    if (jj < cl) {
      int p = base + cs + jj;
      sv = src_sorted[p];
      float a = ap[(size_t)p * 4 + h] + aldh;
      if (asrc_g) a += asrc_g[(size_t)sv * 4 + h];
      a = a > 0.f ? a : SLOPEv * a;
      w = __expf(a);
      den += w;
    }
    int cl4 = (cl + 3) & ~3;   // lanes j>=cl have w=0, sv=0 (harmless hot row-0 load)
    for (int j0 = 0; j0 < cl4; j0 += 4) {
      int s0 = __shfl(sv, j0 + 0, 16);
      int s1 = __shfl(sv, j0 + 1, 16);
      int s2 = __shfl(sv, j0 + 2, 16);
      int s3 = __shfl(sv, j0 + 3, 16);
      float w0 = __shfl(w, j0 + 0, 16);
      float w1 = __shfl(w, j0 + 1, 16);
      float w2 = __shfl(w, j0 + 2, 16);
      float w3 = __shfl(w, j0 + 3, 16);
      uint4 u0 = *((const uint4*)(hb + ((size_t)s0 << 9)) + lane);
      uint4 u1 = *((const uint4*)(hb + ((size_t)s1 << 9)) + lane);
      uint4 u2 = *((const uint4*)(hb + ((size_t)s2 << 9)) + lane);
      uint4 u3 = *((const uint4*)(hb + ((size_t)s3 << 9)) + lane);
      fma8(acc, w0, u0);
      fma8(acc, w1, u1);
      fma8(acc, w2, u2);
      fma8(acc, w3, u3);
    }
  }

  // self loop
  fma8(acc, wl, uself);

  // denominator: reduce over the 16 j-slots within each head group
#pragma unroll
  for (int off = 8; off; off >>= 1) den += __shfl_xor(den, off, 16);
  den += wl;
  float rden = 1.f / (den + 1e-16f);

  // epilogue
  const float4* bp = (const float4*)(bias + lane * 8);
  float4 b0 = bp[0], b1 = bp[1];
  float bv[8] = {b0.x, b0.y, b0.z, b0.w, b1.x, b1.y, b1.z, b1.w};
  float r[8];
#pragma unroll
  for (int q = 0; q < 8; q++) {
    float t = acc[q] * rden + bv[q];
    r[q] = t > 0.f ? t : expm1f(t);
  }
  if (outf) {
    float* op = outf + (size_t)n * HCv + lane * 8;
    nt_store16(op, __float_as_uint(r[0]), __float_as_uint(r[1]),
               __float_as_uint(r[2]), __float_as_uint(r[3]));
    nt_store16(op + 4, __float_as_uint(r[4]), __float_as_uint(r[5]),
               __float_as_uint(r[6]), __float_as_uint(r[7]));
  }
  if (outb) {
    uint4 o;
    o.x = (unsigned)f2b(r[0]) | ((unsigned)f2b(r[1]) << 16);
    o.y = (unsigned)f2b(r[2]) | ((unsigned)f2b(r[3]) << 16);
    o.z = (unsigned)f2b(r[4]) | ((unsigned)f2b(r[5]) << 16);
    o.w = (unsigned)f2b(r[6]) | ((unsigned)f2b(r[7]) << 16);
    ((uint4*)(outb + (size_t)n * HCv))[lane] = o;   // normal store: re-read by gemm2
  }
}

// ---------------------------------------------------------------- launch
static inline char* take(char*& p, size_t bytes) {
  char* r = p;
  p += (bytes + 255) & ~(size_t)255;
  return r;
}

extern "C" void kernel_launch(void* const* d_in, const int* in_sizes, int n_in,
                              void* d_out, int out_size, void* d_ws, size_t ws_size,
                              hipStream_t stream) {
  (void)in_sizes; (void)n_in; (void)out_size; (void)ws_size;
  const float* x   = (const float*)d_in[0];
  const int*   ei  = (const int*)d_in[1];
  const float* ea  = (const float*)d_in[2];
  const float* W1  = (const float*)d_in[3];
  const float* as1 = (const float*)d_in[4];
  const float* ad1 = (const float*)d_in[5];
  const float* We1 = (const float*)d_in[6];
  const float* ae1 = (const float*)d_in[7];
  const float* b1  = (const float*)d_in[8];
  const float* W2  = (const float*)d_in[9];
  const float* as2 = (const float*)d_in[10];
  const float* ad2 = (const float*)d_in[11];
  const float* We2 = (const float*)d_in[12];
  const float* ae2 = (const float*)d_in[13];
  const float* b2  = (const float*)d_in[14];
  float* out = (float*)d_out;

  char* p = (char*)d_ws;
  ushort* hb        = (ushort*)take(p, (size_t)NNODE * HCv * 2);
  float* al_src     = (float*)take(p, (size_t)NNODE * 4 * 4);
  float* al_dst     = (float*)take(p, (size_t)NNODE * 4 * 4);
  float* ap         = (float*)take(p, (size_t)NEDGE * 4 * 4);
  float* ale2s      = (float*)take(p, (size_t)NEDGE * 4 * 4);
  int*   src_sorted = (int*)take(p, (size_t)NEDGE * 4);
  int*   eid_sorted = (int*)take(p, (size_t)NEDGE * 4);
  int*   row_ptr    = (int*)take(p, (size_t)(NNODE + 1) * 4);
  float* partials   = (float*)take(p, (size_t)MEANBLK * EDv * 4);
  ushort* Bt1       = (ushort*)take(p, (size_t)HCv * DINv * 2);
  ushort* Bt2       = (ushort*)take(p, (size_t)HCv * HCv * 2);
  char* zero_begin = p;
  int*   deg        = (int*)take(p, (size_t)NNODE * 4);
  int*   cursor     = (int*)take(p, (size_t)NNODE * 4);
  size_t zero_len = (size_t)(p - zero_begin);
  float* v1         = (float*)take(p, 64 * 4);
  float* v2         = (float*)take(p, 64 * 4);
  float* loop1      = (float*)take(p, 4 * 4);
  float* loop2      = (float*)take(p, 4 * 4);
  int*   flag       = (int*)take(p, 4);

  // scratch carved out of d_out (102.4 MB): xb dead after layer-1 gemm,
  // h1b dead after layer-2 gemm; final out written only by the last node_kernel.
  ushort* xb  = (ushort*)d_out;                                       // 12.8 MB
  ushort* h1b = (ushort*)((char*)d_out + (size_t)16 * 1024 * 1024);   // 51.2 MB

  hipMemsetAsync(zero_begin, 0, zero_len, stream);

  const int NGEMM = 4 * ((NNODE + 127) / 128);   // 1564

  detect_kernel<<<1, 256, 0, stream>>>(ei, flag);
  prep_misc_kernel<<<NCOUNT + MEANBLK + 1 + (CONVN + DINv * HCv + HCv * HCv + 255) / 256, 256,
                     0, stream>>>(ei, flag, deg, ea, partials, We1, ae1, We2, ae2, v1, v2,
                                  x, W1, W2, xb, Bt1, Bt2);
  scan_fold_kernel<<<2, 1024, 0, stream>>>(deg, row_ptr, partials, v1, v2, loop1, loop2);

  // ---- layer 1 (gemm + scatter tail fused)
  gemm_mfma_kernel<<<NGEMM + NCOUNT, 256, 0, stream>>>(
      xb, Bt1, hb, NNODE, DINv, as1, ad1, al_src, al_dst,
      NGEMM, ei, flag, row_ptr, cursor, eid_sorted);
  apre1_kernel<<<(NEDGE + 255) / 256, 256, 0, stream>>>(eid_sorted, ei, flag, ea, al_src,
                                                        v1, v2, ap, ale2s, src_sorted);
  node_kernel<<<(NNODE + 3) / 4, 256, 0, stream>>>(hb, al_src, al_dst, ap, loop1, row_ptr,
                                                   src_sorted, b1, (const float*)nullptr,
                                                   (float*)nullptr, h1b);

  // ---- layer 2 (no scatter tail; apre2 folded into node via asrc_g)
  gemm_mfma_kernel<<<NGEMM, 256, 0, stream>>>(
      h1b, Bt2, hb, NNODE, HCv, as2, ad2, al_src, al_dst,
      NGEMM, ei, flag, row_ptr, cursor, eid_sorted);
  node_kernel<<<(NNODE + 3) / 4, 256, 0, stream>>>(hb, al_src, al_dst, ale2s, loop2, row_ptr,
                                                   src_sorted, b2, al_src,
                                                   out, (ushort*)nullptr);
}